// Round 12
// baseline (318.290 us; speedup 1.0000x reference)
//
#include <hip/hip_runtime.h>
#include <hip/hip_bf16.h>
#include <cstddef>

#define Bz 8
#define Nn 16384
#define MD 256
#define Ff 32
#define Hh 4
#define Gg 32
#define G3v 32768
#define CKV 140
#define NG 32            // B*H groups
#define NBX 31           // x0 in [0,30]
#define NBY 31           // y0 in [0,30]
#define NBZ 31           // z0 in [0,30]
#define NB2 953312       // NG*NBX*NBY*NBZ
#define NCH 931          // ceil(NB2/1024)

using bf16x8 = __attribute__((ext_vector_type(8))) short;
using f32x16 = __attribute__((ext_vector_type(16))) float;

__device__ __forceinline__ unsigned bf16rne(float f) {
    unsigned u = __float_as_uint(f);
    return (u + 0x7fffu + ((u >> 16) & 1u)) >> 16;
}
__device__ __forceinline__ unsigned cvt2(float lo, float hi) {
    __hip_bfloat162 h = __float22bfloat162_rn(make_float2(lo, hi));
    union { __hip_bfloat162 b; unsigned u; } c;
    c.b = h;
    return c.u;
}

// ---------------- Pass 0: W -> bf16, MFMA-fragment order [k>>3][m][k&7], pad m to 160 ----
__global__ __launch_bounds__(256) void prep_w_kernel(const float* __restrict__ W,
                                                     unsigned short* __restrict__ Wbf)
{
    const int idx = blockIdx.x * 256 + threadIdx.x;   // 0..40959
    const int e    = idx & 7;
    const int rest = idx >> 3;
    const int m    = rest % 160;
    const int kg   = rest / 160;
    const int k    = (kg << 3) + e;
    Wbf[idx] = (m < CKV) ? (unsigned short)bf16rne(W[m * MD + k]) : (unsigned short)0;
}

// ---------------- Pass 1: kv = W·X via bf16 MFMA — LDS-free, fused BN statistics ----------------
// Grid: 1024 blocks (b = bid>>7, n0 = (bid&127)*128); 256 threads = 4 waves.
// Wave w owns cols [n0+w*32, +32); lane = (ln, hi). X loaded directly from global
// (coalesced 128B per k-row), converted via v_cvt_pk_bf16_f32; W fragments from L2.
__global__ __launch_bounds__(256, 4) void gemm_stats_kernel(
    const float* __restrict__ X, const unsigned short* __restrict__ Wbf,
    float* __restrict__ vals, float* __restrict__ keys,
    float* __restrict__ gsum, float* __restrict__ gsq)
{
    __shared__ float red[280];

    const int bid = blockIdx.x;
    const int b   = bid >> 7;
    const int n0  = (bid & 127) << 7;
    const int t   = threadIdx.x;
    const int w   = t >> 6;
    const int ln  = t & 31;
    const int hi  = (t >> 5) & 1;
    const int col = n0 + (w << 5) + ln;

    f32x16 acc[5];
    #pragma unroll
    for (int mt = 0; mt < 5; ++mt)
        #pragma unroll
        for (int j = 0; j < 16; ++j) acc[mt][j] = 0.f;

    const float* Xc = X + (size_t)b * MD * Nn + col;

    #pragma unroll 4
    for (int kq = 0; kq < 16; ++kq) {
        const int grp = (kq << 1) + hi;              // k-octet 0..31 (per-lane)
        const float* xp = Xc + ((size_t)(grp << 3)) * Nn;
        const float x0 = xp[0];
        const float x1 = xp[(size_t)Nn];
        const float x2 = xp[(size_t)Nn * 2];
        const float x3 = xp[(size_t)Nn * 3];
        const float x4 = xp[(size_t)Nn * 4];
        const float x5 = xp[(size_t)Nn * 5];
        const float x6 = xp[(size_t)Nn * 6];
        const float x7 = xp[(size_t)Nn * 7];
        union { bf16x8 v; unsigned u[4]; } bfu;
        bfu.u[0] = cvt2(x0, x1);
        bfu.u[1] = cvt2(x2, x3);
        bfu.u[2] = cvt2(x4, x5);
        bfu.u[3] = cvt2(x6, x7);
        const unsigned short* wp = Wbf + (((size_t)grp * 160) << 3);
        #pragma unroll
        for (int mt = 0; mt < 5; ++mt) {
            const bf16x8 af = *reinterpret_cast<const bf16x8*>(wp + (((mt << 5) + ln) << 3));
            acc[mt] = __builtin_amdgcn_mfma_f32_32x32x16_bf16(af, bfu.v, acc[mt], 0, 0, 0);
        }
    }

    // ---- write kv: keys -> (B,H,3,N), vals -> (B,H,N,F) ----
    const int n = col;
    #pragma unroll
    for (int mt = 0; mt < 5; ++mt)
        #pragma unroll
        for (int reg = 0; reg < 16; ++reg) {
            const int ml = (reg & 3) + ((reg >> 2) << 3) + (hi << 2);
            const int c  = mt * 32 + ml;
            const float v = acc[mt][reg];
            if (c < 12) {
                const int hh = c / 3, kk2 = c - (c / 3) * 3;
                keys[(size_t)((b * Hh + hh) * 3 + kk2) * Nn + n] = v;
            } else if (c < CKV) {
                const int cv = c - 12;
                vals[((size_t)(b * Hh + (cv >> 5)) * Nn + n) * Ff + (cv & 31)] = v;
            }
        }

    // ---- BN statistics: 32-lane shuffle reduce over n, then LDS + global atomics ----
    red[t] = 0.f;
    if (t < 24) red[256 + t] = 0.f;
    __syncthreads();
    #pragma unroll
    for (int mt = 0; mt < 5; ++mt)
        #pragma unroll
        for (int reg = 0; reg < 16; ++reg) {
            if (mt == 4 && reg >= 8) continue;
            const int ml = (reg & 3) + ((reg >> 2) << 3) + (hi << 2);
            const int c  = mt * 32 + ml;
            float s = acc[mt][reg];
            float q = s * s;
            #pragma unroll
            for (int off = 1; off < 32; off <<= 1) {
                s += __shfl_xor(s, off);
                q += __shfl_xor(q, off);
            }
            if (ln == 0 && c < CKV) {
                atomicAdd(&red[c], s);
                atomicAdd(&red[140 + c], q);
            }
        }
    __syncthreads();
    if (t < CKV) {
        atomicAdd(&gsum[t], red[t]);
        atomicAdd(&gsq[t],  red[140 + t]);
    }
}

// ---------------- Pass 2: finalize BN affine params ----------------
__global__ void finalize_kernel(const float* __restrict__ gsum, const float* __restrict__ gsq,
                                const float* __restrict__ kg, const float* __restrict__ kb,
                                const float* __restrict__ vg, const float* __restrict__ vb,
                                float* __restrict__ scale, float* __restrict__ shift)
{
    const int c = threadIdx.x;
    if (c < CKV) {
        const float inv = 1.f / (float)(Bz * Nn);
        const float m = gsum[c] * inv;
        const float v = fmaf(-m, m, gsq[c] * inv);
        float ga, be;
        if (c < 12) { ga = kg[c]; be = kb[c]; }
        else        { ga = vg[c - 12]; be = vb[c - 12]; }
        const float sc = ga * rsqrtf(v + 1e-5f);
        scale[c] = sc;
        shift[c] = fmaf(-m, sc, be);
    }
}

// ---------------- Pass 3a: per-point transform -> record + (g,x0,y0,z0) histogram ----------------
__global__ __launch_bounds__(256) void points_kernel(
    const float* __restrict__ keys, const float* __restrict__ orig,
    const float* __restrict__ Rm, const float* __restrict__ tv,
    const float* __restrict__ scale, const float* __restrict__ shift,
    float4* __restrict__ rec, int* __restrict__ cnt)
{
    const int bid = blockIdx.x;
    const int g   = bid >> 6;
    const int b   = g >> 2;
    const int h   = g & 3;
    const int t   = threadIdx.x;
    const int n   = ((bid & 63) << 8) + t;

    __shared__ float sR[9], st3[3], ksc[3], ksh[3];
    if (t < 9)       sR[t] = Rm[h * 9 + t];
    else if (t < 12) st3[t - 9] = tv[h * 3 + (t - 9)];
    else if (t < 15) { ksc[t - 12] = scale[h * 3 + (t - 12)];
                       ksh[t - 12] = shift[h * 3 + (t - 12)]; }
    __syncthreads();

    const float k0 = fmaf(keys[(size_t)(g * 3 + 0) * Nn + n], ksc[0], ksh[0]);
    const float k1 = fmaf(keys[(size_t)(g * 3 + 1) * Nn + n], ksc[1], ksh[1]);
    const float k2 = fmaf(keys[(size_t)(g * 3 + 2) * Nn + n], ksc[2], ksh[2]);
    const float p0 = orig[(size_t)(b * 3 + 0) * Nn + n] + k0;
    const float p1 = orig[(size_t)(b * 3 + 1) * Nn + n] + k1;
    const float p2 = orig[(size_t)(b * 3 + 2) * Nn + n] + k2;

    int   idx[3];
    float loc[3];
    #pragma unroll
    for (int d = 0; d < 3; ++d) {
        const float tk = fmaf(sR[d*3+0], p0, fmaf(sR[d*3+1], p1, fmaf(sR[d*3+2], p2, st3[d])));
        const float la = tanhf(tk);
        const float po = (la + 1.f) * 15.5f;
        float fi = floorf(po);
        fi = fminf(fmaxf(fi, 0.f), 30.f);
        idx[d] = (int)fi;
        loc[d] = po - fi;
    }

    const unsigned meta = (unsigned)n | ((unsigned)idx[2] << 14) |
                          ((unsigned)idx[1] << 19) | ((unsigned)idx[0] << 24);
    float4 r;
    r.x = __uint_as_float(meta);
    r.y = loc[0]; r.z = loc[1]; r.w = loc[2];
    rec[(size_t)g * Nn + n] = r;
    const int key = ((g * NBX + idx[0]) * NBY + idx[1]) * NBZ + idx[2];
    atomicAdd(&cnt[key], 1);
}

// ---------------- Pass 3b: hierarchical exclusive scan over 953312 bins ----------------
__global__ __launch_bounds__(256) void scan1_kernel(const int* __restrict__ cnt,
                                                    int* __restrict__ bsum)
{
    __shared__ int s[256];
    const int t = threadIdx.x;
    const int i = blockIdx.x * 1024 + t * 4;
    int v = 0;
    #pragma unroll
    for (int j = 0; j < 4; ++j) { const int idx = i + j; if (idx < NB2) v += cnt[idx]; }
    s[t] = v;
    __syncthreads();
    for (int off = 128; off > 0; off >>= 1) {
        if (t < off) s[t] += s[t + off];
        __syncthreads();
    }
    if (t == 0) bsum[blockIdx.x] = s[0];
}

__global__ __launch_bounds__(1024) void scan2_kernel(const int* __restrict__ bsum,
                                                     int* __restrict__ bscan)
{
    __shared__ int s[1024];
    const int t = threadIdx.x;
    const int v = (t < NCH) ? bsum[t] : 0;
    s[t] = v;
    __syncthreads();
    for (int off = 1; off < 1024; off <<= 1) {
        const int x = (t >= off) ? s[t - off] : 0;
        __syncthreads();
        s[t] += x;
        __syncthreads();
    }
    if (t < NCH) bscan[t] = s[t] - v;   // exclusive
}

__global__ __launch_bounds__(256) void scan3_kernel(const int* __restrict__ cnt,
                                                    const int* __restrict__ bscan,
                                                    int* __restrict__ basep,
                                                    int* __restrict__ cursor)
{
    __shared__ int s[256];
    const int t = threadIdx.x;
    const int i = blockIdx.x * 1024 + t * 4;
    int c[4], l[4];
    int sum = 0;
    #pragma unroll
    for (int j = 0; j < 4; ++j) {
        const int idx = i + j;
        c[j] = (idx < NB2) ? cnt[idx] : 0;
        l[j] = sum; sum += c[j];
    }
    s[t] = sum;
    __syncthreads();
    for (int off = 1; off < 256; off <<= 1) {
        const int x = (t >= off) ? s[t - off] : 0;
        __syncthreads();
        s[t] += x;
        __syncthreads();
    }
    const int off0 = bscan[blockIdx.x] + s[t] - sum;
    #pragma unroll
    for (int j = 0; j < 4; ++j) {
        const int idx = i + j;
        if (idx < NB2) { basep[idx] = off0 + l[j]; cursor[idx] = off0 + l[j]; }
    }
}

// ---------------- Pass 3c: counting-sort records into (g,x0,y0,z0) bins ----------------
__global__ __launch_bounds__(256) void fill_kernel(
    const float4* __restrict__ rec, int* __restrict__ cursor,
    float4* __restrict__ binned)
{
    const int bid = blockIdx.x;
    const int g   = bid >> 6;
    const int t   = threadIdx.x;
    const int n   = ((bid & 63) << 8) + t;
    const float4 r = rec[(size_t)g * Nn + n];
    const unsigned meta = __float_as_uint(r.x);
    const int x0 = (meta >> 24) & 31;
    const int y0 = (meta >> 19) & 31;
    const int z0 = (meta >> 14) & 31;
    const int key = ((g * NBX + x0) * NBY + y0) * NBZ + z0;
    const int pos = atomicAdd(&cursor[key], 1);
    binned[pos] = r;
}

// ---------------- Pass 3d: gather — whole-wave rows, z-run regs, 8-deep prefetch ----------------
#define PROC(q, vq)                                                          \
{                                                                            \
    const unsigned mq = __float_as_uint((q).x);                              \
    const int zq = (int)((mq >> 14) & 31u);                                  \
    if (zq != zcur) {                                                        \
        if (zcur >= 0) { const int zr = zcur + zc;                           \
                         tg[(zr << 5) + (f ^ zr)] += acc; }                  \
        acc = 0.f; zcur = zq;                                                \
    }                                                                        \
    const int my = (int)((mq >> 19) & 31u);                                  \
    const float wx = dx ? (1.f - (q).y) : (q).y;                             \
    const float wy = (my == y) ? (1.f - (q).z) : (q).z;                      \
    const float wz = zc ? (q).w : (1.f - (q).w);                             \
    acc = fmaf(wx * wy * wz, fmaf(vq, scf, shf), acc);                       \
}

__global__ __launch_bounds__(1024) void gather_kernel(
    const float* __restrict__ vals, const float4* __restrict__ binned,
    const int* __restrict__ basep, const int* __restrict__ cnt,
    const float* __restrict__ scale, const float* __restrict__ shift,
    float* __restrict__ out)
{
    __shared__ float tile[16384];
    __shared__ float sscale[32], sshift[32];

    const int bid = blockIdx.x;
    const int g   = bid & 31;
    const int x   = (bid >> 5) & 31;
    const int yh  = bid >> 10;
    const int h   = g & 3;
    const int t   = threadIdx.x;

    {
        const float4 z4 = make_float4(0.f, 0.f, 0.f, 0.f);
        #pragma unroll
        for (int i = 0; i < 4; ++i)
            *reinterpret_cast<float4*>(&tile[(t << 2) + (i << 12)]) = z4;
    }
    if (t < 32) { sscale[t] = scale[12 + h * 32 + t]; sshift[t] = shift[12 + h * 32 + t]; }
    __syncthreads();

    const int f  = t & 31;
    const int zc = (t >> 5) & 1;
    const int w  = t >> 6;            // wave id 0..15
    const int y  = (yh << 4) + w;     // owned output row
    const float scf = sscale[f], shf = sshift[f];
    const float* vg = vals + ((size_t)g << 19);   // g * Nn * Ff
    float* const tg = &tile[w << 10];             // wave-private 32x32 tile

    float acc = 0.f;
    int zcur = -2;

    const int y0lo = (y > 0)  ? y - 1 : 0;
    const int y0hi = (y < 31) ? y     : 30;

    #pragma unroll
    for (int dx = 0; dx < 2; ++dx) {
        const int x0 = x - 1 + dx;
        if ((unsigned)x0 > 30u) continue;
        const int kb = ((g * NBX + x0) * NBY + y0lo) * NBZ;
        const int ke = ((g * NBX + x0) * NBY + y0hi) * NBZ + 30;
        int r       = basep[kb];
        const int e = basep[ke] + cnt[ke];

        for (; r + 8 <= e; r += 8) {
            const float4 q0 = binned[r];
            const float4 q1 = binned[r + 1];
            const float4 q2 = binned[r + 2];
            const float4 q3 = binned[r + 3];
            const float4 q4 = binned[r + 4];
            const float4 q5 = binned[r + 5];
            const float4 q6 = binned[r + 6];
            const float4 q7 = binned[r + 7];
            const float v0 = vg[((__float_as_uint(q0.x) & 16383u) << 5) + f];
            const float v1 = vg[((__float_as_uint(q1.x) & 16383u) << 5) + f];
            const float v2 = vg[((__float_as_uint(q2.x) & 16383u) << 5) + f];
            const float v3 = vg[((__float_as_uint(q3.x) & 16383u) << 5) + f];
            const float v4 = vg[((__float_as_uint(q4.x) & 16383u) << 5) + f];
            const float v5 = vg[((__float_as_uint(q5.x) & 16383u) << 5) + f];
            const float v6 = vg[((__float_as_uint(q6.x) & 16383u) << 5) + f];
            const float v7 = vg[((__float_as_uint(q7.x) & 16383u) << 5) + f];
            PROC(q0, v0); PROC(q1, v1); PROC(q2, v2); PROC(q3, v3);
            PROC(q4, v4); PROC(q5, v5); PROC(q6, v6); PROC(q7, v7);
        }
        for (; r + 4 <= e; r += 4) {
            const float4 q0 = binned[r];
            const float4 q1 = binned[r + 1];
            const float4 q2 = binned[r + 2];
            const float4 q3 = binned[r + 3];
            const float v0 = vg[((__float_as_uint(q0.x) & 16383u) << 5) + f];
            const float v1 = vg[((__float_as_uint(q1.x) & 16383u) << 5) + f];
            const float v2 = vg[((__float_as_uint(q2.x) & 16383u) << 5) + f];
            const float v3 = vg[((__float_as_uint(q3.x) & 16383u) << 5) + f];
            PROC(q0, v0); PROC(q1, v1); PROC(q2, v2); PROC(q3, v3);
        }
        for (; r < e; ++r) {
            const float4 q0 = binned[r];
            const float v0 = vg[((__float_as_uint(q0.x) & 16383u) << 5) + f];
            PROC(q0, v0);
        }
    }
    if (zcur >= 0) {
        const int zr = zcur + zc;
        tg[(zr << 5) + (f ^ zr)] += acc;
    }
    __syncthreads();

    // write out[(g*32+fp)*G3 + x*1024 + yh*512 + row*32 + z]
    float* og = out + ((size_t)g << 20) + (x << 10) + (yh << 9);
    #pragma unroll
    for (int i = 0; i < 16; ++i) {
        const int lin = t + (i << 10);
        const int fp  = lin >> 9;          // 0..31
        const int s   = lin & 511;         // row*32 + z
        const int z   = s & 31;
        og[((size_t)fp << 15) + s] = tile[((s >> 5) << 10) + (z << 5) + (fp ^ z)];
    }
}

// ---------------- Fallback: direct-layout global-atomic scatter ----------------
__global__ __launch_bounds__(256) void scatter_kernel(
    const float* __restrict__ vals, const float* __restrict__ keys,
    const float* __restrict__ orig, const float* __restrict__ Rm,
    const float* __restrict__ tv, const float* __restrict__ scale,
    const float* __restrict__ shift, float* __restrict__ out)
{
    const int bid   = blockIdx.x;
    const int g     = bid >> 5;
    const int chunk = bid & 31;
    const int b     = g >> 2;
    const int h     = g & 3;

    __shared__ float sc[32], sh[32], sR[9], st3[3], ksc[3], ksh[3];
    const int t = threadIdx.x;
    if (t < 32)      { sc[t] = scale[12 + h * 32 + t]; sh[t] = shift[12 + h * 32 + t]; }
    else if (t < 41) { sR[t - 32]  = Rm[h * 9 + (t - 32)]; }
    else if (t < 44) { st3[t - 41] = tv[h * 3 + (t - 41)]; }
    else if (t < 47) { ksc[t - 44] = scale[h * 3 + (t - 44)];
                       ksh[t - 44] = shift[h * 3 + (t - 44)]; }
    __syncthreads();

    float* const og = out + ((size_t)g << 20);

    #pragma unroll
    for (int pp = 0; pp < 2; ++pp) {
        const int n = (chunk << 9) + (pp << 8) + t;

        const float k0 = fmaf(keys[(size_t)(g * 3 + 0) * Nn + n], ksc[0], ksh[0]);
        const float k1 = fmaf(keys[(size_t)(g * 3 + 1) * Nn + n], ksc[1], ksh[1]);
        const float k2 = fmaf(keys[(size_t)(g * 3 + 2) * Nn + n], ksc[2], ksh[2]);
        const float p0 = orig[(size_t)(b * 3 + 0) * Nn + n] + k0;
        const float p1 = orig[(size_t)(b * 3 + 1) * Nn + n] + k1;
        const float p2 = orig[(size_t)(b * 3 + 2) * Nn + n] + k2;

        int   idx[3];
        float loc[3];
        #pragma unroll
        for (int d = 0; d < 3; ++d) {
            const float tk = fmaf(sR[d*3+0], p0, fmaf(sR[d*3+1], p1, fmaf(sR[d*3+2], p2, st3[d])));
            const float la = tanhf(tk);
            const float po = (la + 1.f) * 15.5f;
            float fi = floorf(po);
            fi = fminf(fmaxf(fi, 0.f), 30.f);
            idx[d] = (int)fi;
            loc[d] = po - fi;
        }
        const int cell = (idx[0] * Gg + idx[1]) * Gg + idx[2];

        float v[32];
        const float4* vp = reinterpret_cast<const float4*>(vals + ((size_t)g * Nn + n) * Ff);
        #pragma unroll
        for (int q = 0; q < 8; ++q) {
            const float4 xq = vp[q];
            v[4*q+0] = fmaf(xq.x, sc[4*q+0], sh[4*q+0]);
            v[4*q+1] = fmaf(xq.y, sc[4*q+1], sh[4*q+1]);
            v[4*q+2] = fmaf(xq.z, sc[4*q+2], sh[4*q+2]);
            v[4*q+3] = fmaf(xq.w, sc[4*q+3], sh[4*q+3]);
        }

        const float wx1 = loc[0], wx0 = 1.f - loc[0];
        const float wy1 = loc[1], wy0 = 1.f - loc[1];
        const float wz1 = loc[2], wz0 = 1.f - loc[2];
        const float cw[8] = { wx0*wy0*wz0, wx0*wy0*wz1, wx0*wy1*wz0, wx0*wy1*wz1,
                              wx1*wy0*wz0, wx1*wy0*wz1, wx1*wy1*wz0, wx1*wy1*wz1 };
        const int  co[8] = { 0, 1, 32, 33, 1024, 1025, 1056, 1057 };

        #pragma unroll
        for (int ff = 0; ff < 32; ++ff) {
            float* const pf = og + (size_t)ff * G3v + cell;
            const float vf = v[ff];
            #pragma unroll
            for (int c8 = 0; c8 < 8; ++c8) {
                atomicAdd(pf + co[c8], cw[c8] * vf);
            }
        }
    }
}

extern "C" void kernel_launch(void* const* d_in, const int* in_sizes, int n_in,
                              void* d_out, int out_size, void* d_ws, size_t ws_size,
                              hipStream_t stream)
{
    const float* X    = (const float*)d_in[0];
    const float* orig = (const float*)d_in[1];
    const float* W    = (const float*)d_in[2];
    const float* kg   = (const float*)d_in[3];
    const float* kb   = (const float*)d_in[4];
    const float* vg   = (const float*)d_in[5];
    const float* vb   = (const float*)d_in[6];
    const float* Rm   = (const float*)d_in[7];
    const float* tv   = (const float*)d_in[8];
    float* out = (float*)d_out;
    float* ws  = (float*)d_ws;

    // float-offset workspace layout
    float* vals  = ws;                          // 16,777,216
    float* keys  = ws + 16777216;               //  1,572,864
    float* gsum  = ws + 18350080;               // 140
    float* gsq   = gsum + 140;
    float* scale = gsum + 280;
    float* shift = scale + 140;
    int*   cnt    = (int*)(ws + 18350848);      // 953,312
    int*   basep  = (int*)(ws + 19304160);      // 953,312
    int*   cursor = (int*)(ws + 20257472);      // 953,312
    int*   bsum   = (int*)(ws + 21210784);      // 1,024
    int*   bscan  = (int*)(ws + 21211808);      // 1,024
    float4* rec    = (float4*)(ws + 21212832);  // 524,288 float4
    float4* binned = (float4*)(ws + 23309984);  // 524,288 float4
    unsigned short* Wbf = (unsigned short*)(ws + 25407136); // 40,960 bf16
    const size_t need_bytes = (size_t)25427616 * sizeof(float);   // ~101.7 MiB

    hipMemsetAsync(gsum, 0, 280 * sizeof(float), stream);

    prep_w_kernel<<<160, 256, 0, stream>>>(W, Wbf);
    gemm_stats_kernel<<<1024, 256, 0, stream>>>(X, Wbf, vals, keys, gsum, gsq);
    finalize_kernel<<<1, 256, 0, stream>>>(gsum, gsq, kg, kb, vg, vb, scale, shift);

    if (ws_size >= need_bytes) {
        hipMemsetAsync(cnt, 0, (size_t)NB2 * sizeof(int), stream);
        points_kernel<<<2048, 256, 0, stream>>>(keys, orig, Rm, tv, scale, shift, rec, cnt);
        scan1_kernel<<<NCH, 256, 0, stream>>>(cnt, bsum);
        scan2_kernel<<<1, 1024, 0, stream>>>(bsum, bscan);
        scan3_kernel<<<NCH, 256, 0, stream>>>(cnt, bscan, basep, cursor);
        fill_kernel<<<2048, 256, 0, stream>>>(rec, cursor, binned);
        gather_kernel<<<2048, 1024, 0, stream>>>(vals, binned, basep, cnt, scale, shift, out);
    } else {
        hipMemsetAsync(out, 0, (size_t)out_size * sizeof(float), stream);
        scatter_kernel<<<1024, 256, 0, stream>>>(vals, keys, orig, Rm, tv, scale, shift, out);
    }
}

// Round 13
// 306.615 us; speedup vs baseline: 1.0381x; 1.0381x over previous
//
#include <hip/hip_runtime.h>
#include <hip/hip_bf16.h>
#include <cstddef>

#define Bz 8
#define Nn 16384
#define MD 256
#define Ff 32
#define Hh 4
#define Gg 32
#define G3v 32768
#define CKV 140
#define NG 32            // B*H groups
#define NBX 31           // x0 in [0,30]
#define NBY 31           // y0 in [0,30]
#define NBZ 31           // z0 in [0,30]
#define NB2 953312       // NG*NBX*NBY*NBZ
#define NCH 931          // ceil(NB2/1024)

using bf16x8 = __attribute__((ext_vector_type(8))) short;
using f32x16 = __attribute__((ext_vector_type(16))) float;

__device__ __forceinline__ unsigned bf16rne(float f) {
    unsigned u = __float_as_uint(f);
    return (u + 0x7fffu + ((u >> 16) & 1u)) >> 16;
}
__device__ __forceinline__ unsigned cvt2(float lo, float hi) {
    __hip_bfloat162 hb = __float22bfloat162_rn(make_float2(lo, hi));
    union { __hip_bfloat162 b; unsigned u; } c;
    c.b = hb;
    return c.u;
}

// ---------------- Pass 0: W -> bf16, MFMA-fragment order [k>>3][m][k&7], pad m to 160 ----
__global__ __launch_bounds__(256) void prep_w_kernel(const float* __restrict__ W,
                                                     unsigned short* __restrict__ Wbf)
{
    const int idx = blockIdx.x * 256 + threadIdx.x;   // 0..40959
    const int e    = idx & 7;
    const int rest = idx >> 3;
    const int m    = rest % 160;
    const int kg   = rest / 160;
    const int k    = (kg << 3) + e;
    Wbf[idx] = (m < CKV) ? (unsigned short)bf16rne(W[m * MD + k]) : (unsigned short)0;
}

// ---------------- Pass 1: kv = W·X via bf16 MFMA (LDS-staged), fused BN statistics ----------------
// Grid: 1024 blocks (b = bid>>7, n0 = (bid&127)*128); 256 threads = 4 waves.
__global__ __launch_bounds__(256, 3) void gemm_stats_kernel(
    const float* __restrict__ X, const unsigned short* __restrict__ Wbf,
    float* __restrict__ vals, float* __restrict__ keys,
    float* __restrict__ gsum, float* __restrict__ gsq)
{
    __shared__ unsigned XlU[4096];   // 16 KB  : [k>>3][n][k&7] bf16 pairs
    __shared__ unsigned WlU[5120];   // 20 KB  : dword copy of Wbf K-slice
    __shared__ float red[280];

    const int bid = blockIdx.x;
    const int b   = bid >> 7;
    const int n0  = (bid & 127) << 7;
    const int t   = threadIdx.x;
    const int w   = t >> 6;
    const int ln  = t & 31;
    const int hi  = (t >> 5) & 1;

    f32x16 acc[5];
    #pragma unroll
    for (int mt = 0; mt < 5; ++mt)
        #pragma unroll
        for (int j = 0; j < 16; ++j) acc[mt][j] = 0.f;

    for (int ks = 0; ks < 4; ++ks) {
        const int k0 = ks << 6;
        if (ks > 0) __syncthreads();

        // stage X tile [64 k][128 n] -> bf16 transposed [k>>3][n][k&7]
        #pragma unroll
        for (int it = 0; it < 4; ++it) {
            const int a  = t + (it << 8);
            const int kp = a >> 5;            // k-pair 0..31 (k = 2kp, 2kp+1)
            const int n4 = (a & 31) << 2;
            const float4 r0 = *reinterpret_cast<const float4*>(
                X + (size_t)(b * MD + k0 + 2 * kp) * Nn + n0 + n4);
            const float4 r1 = *reinterpret_cast<const float4*>(
                X + (size_t)(b * MD + k0 + 2 * kp + 1) * Nn + n0 + n4);
            const int base = ((kp >> 2) << 9) + (n4 << 2) + (kp & 3);
            XlU[base]      = cvt2(r0.x, r1.x);
            XlU[base + 4]  = cvt2(r0.y, r1.y);
            XlU[base + 8]  = cvt2(r0.z, r1.z);
            XlU[base + 12] = cvt2(r0.w, r1.w);
        }
        // stage W slice: 5120 dwords, linear copy
        {
            const unsigned* src = reinterpret_cast<const unsigned*>(Wbf) + ks * 5120;
            #pragma unroll
            for (int i = 0; i < 5; ++i) {
                const int d4 = (t + (i << 8)) << 2;
                *reinterpret_cast<uint4*>(&WlU[d4]) =
                    *reinterpret_cast<const uint4*>(&src[d4]);
            }
        }
        __syncthreads();

        const short* xs = reinterpret_cast<const short*>(XlU);
        const short* ws = reinterpret_cast<const short*>(WlU);
        #pragma unroll
        for (int kk = 0; kk < 4; ++kk) {
            const int grp = (kk << 1) + hi;
            const bf16x8 bf = *reinterpret_cast<const bf16x8*>(
                xs + (((grp << 7) + (w << 5) + ln) << 3));
            #pragma unroll
            for (int mt = 0; mt < 5; ++mt) {
                const bf16x8 af = *reinterpret_cast<const bf16x8*>(
                    ws + ((grp * 160 + (mt << 5) + ln) << 3));
                acc[mt] = __builtin_amdgcn_mfma_f32_32x32x16_bf16(af, bf, acc[mt], 0, 0, 0);
            }
        }
    }

    // ---- write kv: keys -> (B,H,3,N), vals -> (B,H,N,F) ----
    const int n = n0 + (w << 5) + ln;
    #pragma unroll
    for (int mt = 0; mt < 5; ++mt)
        #pragma unroll
        for (int reg = 0; reg < 16; ++reg) {
            const int ml = (reg & 3) + ((reg >> 2) << 3) + (hi << 2);
            const int c  = mt * 32 + ml;
            const float v = acc[mt][reg];
            if (c < 12) {
                const int hh = c / 3, kk2 = c - (c / 3) * 3;
                keys[(size_t)((b * Hh + hh) * 3 + kk2) * Nn + n] = v;
            } else if (c < CKV) {
                const int cv = c - 12;
                vals[((size_t)(b * Hh + (cv >> 5)) * Nn + n) * Ff + (cv & 31)] = v;
            }
        }

    // ---- BN statistics: 32-lane shuffle reduce over n, then LDS + global atomics ----
    red[t] = 0.f;
    if (t < 24) red[256 + t] = 0.f;
    __syncthreads();
    #pragma unroll
    for (int mt = 0; mt < 5; ++mt)
        #pragma unroll
        for (int reg = 0; reg < 16; ++reg) {
            if (mt == 4 && reg >= 8) continue;
            const int ml = (reg & 3) + ((reg >> 2) << 3) + (hi << 2);
            const int c  = mt * 32 + ml;
            float s = acc[mt][reg];
            float q = s * s;
            #pragma unroll
            for (int off = 1; off < 32; off <<= 1) {
                s += __shfl_xor(s, off);
                q += __shfl_xor(q, off);
            }
            if (ln == 0 && c < CKV) {
                atomicAdd(&red[c], s);
                atomicAdd(&red[140 + c], q);
            }
        }
    __syncthreads();
    if (t < CKV) {
        atomicAdd(&gsum[t], red[t]);
        atomicAdd(&gsq[t],  red[140 + t]);
    }
}

// ---------------- Pass 2: finalize BN affine params ----------------
__global__ void finalize_kernel(const float* __restrict__ gsum, const float* __restrict__ gsq,
                                const float* __restrict__ kg, const float* __restrict__ kb,
                                const float* __restrict__ vg, const float* __restrict__ vb,
                                float* __restrict__ scale, float* __restrict__ shift)
{
    const int c = threadIdx.x;
    if (c < CKV) {
        const float inv = 1.f / (float)(Bz * Nn);
        const float m = gsum[c] * inv;
        const float v = fmaf(-m, m, gsq[c] * inv);
        float ga, be;
        if (c < 12) { ga = kg[c]; be = kb[c]; }
        else        { ga = vg[c - 12]; be = vb[c - 12]; }
        const float sc = ga * rsqrtf(v + 1e-5f);
        scale[c] = sc;
        shift[c] = fmaf(-m, sc, be);
    }
}

// ---------------- Pass 3a: per-point transform -> record + (g,x0,y0,z0) histogram ----------------
__global__ __launch_bounds__(256) void points_kernel(
    const float* __restrict__ keys, const float* __restrict__ orig,
    const float* __restrict__ Rm, const float* __restrict__ tv,
    const float* __restrict__ scale, const float* __restrict__ shift,
    float4* __restrict__ rec, int* __restrict__ cnt)
{
    const int bid = blockIdx.x;
    const int g   = bid >> 6;
    const int b   = g >> 2;
    const int h   = g & 3;
    const int t   = threadIdx.x;
    const int n   = ((bid & 63) << 8) + t;

    __shared__ float sR[9], st3[3], ksc[3], ksh[3];
    if (t < 9)       sR[t] = Rm[h * 9 + t];
    else if (t < 12) st3[t - 9] = tv[h * 3 + (t - 9)];
    else if (t < 15) { ksc[t - 12] = scale[h * 3 + (t - 12)];
                       ksh[t - 12] = shift[h * 3 + (t - 12)]; }
    __syncthreads();

    const float k0 = fmaf(keys[(size_t)(g * 3 + 0) * Nn + n], ksc[0], ksh[0]);
    const float k1 = fmaf(keys[(size_t)(g * 3 + 1) * Nn + n], ksc[1], ksh[1]);
    const float k2 = fmaf(keys[(size_t)(g * 3 + 2) * Nn + n], ksc[2], ksh[2]);
    const float p0 = orig[(size_t)(b * 3 + 0) * Nn + n] + k0;
    const float p1 = orig[(size_t)(b * 3 + 1) * Nn + n] + k1;
    const float p2 = orig[(size_t)(b * 3 + 2) * Nn + n] + k2;

    int   idx[3];
    float loc[3];
    #pragma unroll
    for (int d = 0; d < 3; ++d) {
        const float tk = fmaf(sR[d*3+0], p0, fmaf(sR[d*3+1], p1, fmaf(sR[d*3+2], p2, st3[d])));
        const float la = tanhf(tk);
        const float po = (la + 1.f) * 15.5f;
        float fi = floorf(po);
        fi = fminf(fmaxf(fi, 0.f), 30.f);
        idx[d] = (int)fi;
        loc[d] = po - fi;
    }

    const unsigned meta = (unsigned)n | ((unsigned)idx[2] << 14) |
                          ((unsigned)idx[1] << 19) | ((unsigned)idx[0] << 24);
    float4 r;
    r.x = __uint_as_float(meta);
    r.y = loc[0]; r.z = loc[1]; r.w = loc[2];
    rec[(size_t)g * Nn + n] = r;
    const int key = ((g * NBX + idx[0]) * NBY + idx[1]) * NBZ + idx[2];
    atomicAdd(&cnt[key], 1);
}

// ---------------- Pass 3b: hierarchical exclusive scan over 953312 bins ----------------
__global__ __launch_bounds__(256) void scan1_kernel(const int* __restrict__ cnt,
                                                    int* __restrict__ bsum)
{
    __shared__ int s[256];
    const int t = threadIdx.x;
    const int i = blockIdx.x * 1024 + t * 4;
    int v = 0;
    #pragma unroll
    for (int j = 0; j < 4; ++j) { const int idx = i + j; if (idx < NB2) v += cnt[idx]; }
    s[t] = v;
    __syncthreads();
    for (int off = 128; off > 0; off >>= 1) {
        if (t < off) s[t] += s[t + off];
        __syncthreads();
    }
    if (t == 0) bsum[blockIdx.x] = s[0];
}

__global__ __launch_bounds__(1024) void scan2_kernel(const int* __restrict__ bsum,
                                                     int* __restrict__ bscan)
{
    __shared__ int s[1024];
    const int t = threadIdx.x;
    const int v = (t < NCH) ? bsum[t] : 0;
    s[t] = v;
    __syncthreads();
    for (int off = 1; off < 1024; off <<= 1) {
        const int x = (t >= off) ? s[t - off] : 0;
        __syncthreads();
        s[t] += x;
        __syncthreads();
    }
    if (t < NCH) bscan[t] = s[t] - v;   // exclusive
}

__global__ __launch_bounds__(256) void scan3_kernel(const int* __restrict__ cnt,
                                                    const int* __restrict__ bscan,
                                                    int* __restrict__ basep,
                                                    int* __restrict__ cursor)
{
    __shared__ int s[256];
    const int t = threadIdx.x;
    const int i = blockIdx.x * 1024 + t * 4;
    int c[4], l[4];
    int sum = 0;
    #pragma unroll
    for (int j = 0; j < 4; ++j) {
        const int idx = i + j;
        c[j] = (idx < NB2) ? cnt[idx] : 0;
        l[j] = sum; sum += c[j];
    }
    s[t] = sum;
    __syncthreads();
    for (int off = 1; off < 256; off <<= 1) {
        const int x = (t >= off) ? s[t - off] : 0;
        __syncthreads();
        s[t] += x;
        __syncthreads();
    }
    const int off0 = bscan[blockIdx.x] + s[t] - sum;
    #pragma unroll
    for (int j = 0; j < 4; ++j) {
        const int idx = i + j;
        if (idx < NB2) { basep[idx] = off0 + l[j]; cursor[idx] = off0 + l[j]; }
    }
}

// ---------------- Pass 3c: counting-sort records into (g,x0,y0,z0) bins ----------------
__global__ __launch_bounds__(256) void fill_kernel(
    const float4* __restrict__ rec, int* __restrict__ cursor,
    float4* __restrict__ binned)
{
    const int bid = blockIdx.x;
    const int g   = bid >> 6;
    const int t   = threadIdx.x;
    const int n   = ((bid & 63) << 8) + t;
    const float4 r = rec[(size_t)g * Nn + n];
    const unsigned meta = __float_as_uint(r.x);
    const int x0 = (meta >> 24) & 31;
    const int y0 = (meta >> 19) & 31;
    const int z0 = (meta >> 14) & 31;
    const int key = ((g * NBX + x0) * NBY + y0) * NBZ + z0;
    const int pos = atomicAdd(&cursor[key], 1);
    binned[pos] = r;
}

// ---------------- Pass 3d: gather — whole-wave rows, static weights, z-run regs ----------------
// Grid: 2048 blocks = g | x<<5 | yh<<10; 1024 threads = 16 waves.
// Wave w owns row y = yh*16+w; lane = (f = t&31, zc = (t>>5)&1). Tile 16x32x32 = 64 KB.
// 4 static (dy,dx) bin-ranges per wave: wy/wx compile-time selected — no meta y/x tests.
#define PROC(q, vq, WY)                                                      \
{                                                                            \
    const unsigned mq = __float_as_uint((q).x);                              \
    const int zq = (int)((mq >> 14) & 31u);                                  \
    if (zq != zcur) {                                                        \
        if (zcur >= 0) { const int zr = zcur + zc;                           \
                         tg[(zr << 5) + (f ^ zr)] += acc; }                  \
        acc = 0.f; zcur = zq;                                                \
    }                                                                        \
    const float wx = dx ? (1.f - (q).y) : (q).y;                             \
    const float wz = zc ? (q).w : (1.f - (q).w);                             \
    acc = fmaf(wx * (WY) * wz, fmaf(vq, scf, shf), acc);                     \
}

__global__ __launch_bounds__(1024) void gather_kernel(
    const float* __restrict__ vals, const float4* __restrict__ binned,
    const int* __restrict__ basep, const int* __restrict__ cnt,
    const float* __restrict__ scale, const float* __restrict__ shift,
    float* __restrict__ out)
{
    __shared__ float tile[16384];
    __shared__ float sscale[32], sshift[32];

    const int bid = blockIdx.x;
    const int g   = bid & 31;
    const int x   = (bid >> 5) & 31;
    const int yh  = bid >> 10;
    const int h   = g & 3;
    const int t   = threadIdx.x;

    {
        const float4 z4 = make_float4(0.f, 0.f, 0.f, 0.f);
        #pragma unroll
        for (int i = 0; i < 4; ++i)
            *reinterpret_cast<float4*>(&tile[(t << 2) + (i << 12)]) = z4;
    }
    if (t < 32) { sscale[t] = scale[12 + h * 32 + t]; sshift[t] = shift[12 + h * 32 + t]; }
    __syncthreads();

    const int f  = t & 31;
    const int zc = (t >> 5) & 1;
    const int w  = t >> 6;            // wave id 0..15
    const int y  = (yh << 4) + w;     // owned output row
    const float scf = sscale[f], shf = sshift[f];
    const float* vg = vals + ((size_t)g << 19);   // g * Nn * Ff
    float* const tg = &tile[w << 10];             // wave-private 32x32 tile

    float acc = 0.f;
    int zcur = -2;

    #pragma unroll
    for (int dy = 0; dy < 2; ++dy) {
        const int y0 = y - 1 + dy;                // dy=0: wy=q.z ; dy=1: wy=1-q.z
        if ((unsigned)y0 > 30u) continue;
        #pragma unroll
        for (int dx = 0; dx < 2; ++dx) {
            const int x0 = x - 1 + dx;
            if ((unsigned)x0 > 30u) continue;
            const int kb = ((g * NBX + x0) * NBY + y0) * NBZ;
            int r       = basep[kb];
            const int e = basep[kb + 30] + cnt[kb + 30];

            for (; r + 8 <= e; r += 8) {
                const float4 q0 = binned[r];
                const float4 q1 = binned[r + 1];
                const float4 q2 = binned[r + 2];
                const float4 q3 = binned[r + 3];
                const float4 q4 = binned[r + 4];
                const float4 q5 = binned[r + 5];
                const float4 q6 = binned[r + 6];
                const float4 q7 = binned[r + 7];
                const float v0 = vg[((__float_as_uint(q0.x) & 16383u) << 5) + f];
                const float v1 = vg[((__float_as_uint(q1.x) & 16383u) << 5) + f];
                const float v2 = vg[((__float_as_uint(q2.x) & 16383u) << 5) + f];
                const float v3 = vg[((__float_as_uint(q3.x) & 16383u) << 5) + f];
                const float v4 = vg[((__float_as_uint(q4.x) & 16383u) << 5) + f];
                const float v5 = vg[((__float_as_uint(q5.x) & 16383u) << 5) + f];
                const float v6 = vg[((__float_as_uint(q6.x) & 16383u) << 5) + f];
                const float v7 = vg[((__float_as_uint(q7.x) & 16383u) << 5) + f];
                PROC(q0, v0, dy ? (1.f - q0.z) : q0.z);
                PROC(q1, v1, dy ? (1.f - q1.z) : q1.z);
                PROC(q2, v2, dy ? (1.f - q2.z) : q2.z);
                PROC(q3, v3, dy ? (1.f - q3.z) : q3.z);
                PROC(q4, v4, dy ? (1.f - q4.z) : q4.z);
                PROC(q5, v5, dy ? (1.f - q5.z) : q5.z);
                PROC(q6, v6, dy ? (1.f - q6.z) : q6.z);
                PROC(q7, v7, dy ? (1.f - q7.z) : q7.z);
            }
            for (; r + 4 <= e; r += 4) {
                const float4 q0 = binned[r];
                const float4 q1 = binned[r + 1];
                const float4 q2 = binned[r + 2];
                const float4 q3 = binned[r + 3];
                const float v0 = vg[((__float_as_uint(q0.x) & 16383u) << 5) + f];
                const float v1 = vg[((__float_as_uint(q1.x) & 16383u) << 5) + f];
                const float v2 = vg[((__float_as_uint(q2.x) & 16383u) << 5) + f];
                const float v3 = vg[((__float_as_uint(q3.x) & 16383u) << 5) + f];
                PROC(q0, v0, dy ? (1.f - q0.z) : q0.z);
                PROC(q1, v1, dy ? (1.f - q1.z) : q1.z);
                PROC(q2, v2, dy ? (1.f - q2.z) : q2.z);
                PROC(q3, v3, dy ? (1.f - q3.z) : q3.z);
            }
            for (; r < e; ++r) {
                const float4 q0 = binned[r];
                const float v0 = vg[((__float_as_uint(q0.x) & 16383u) << 5) + f];
                PROC(q0, v0, dy ? (1.f - q0.z) : q0.z);
            }
        }
    }
    if (zcur >= 0) {
        const int zr = zcur + zc;
        tg[(zr << 5) + (f ^ zr)] += acc;
    }
    __syncthreads();

    // write out[(g*32+fp)*G3 + x*1024 + yh*512 + row*32 + z]
    float* og = out + ((size_t)g << 20) + (x << 10) + (yh << 9);
    #pragma unroll
    for (int i = 0; i < 16; ++i) {
        const int lin = t + (i << 10);
        const int fp  = lin >> 9;          // 0..31
        const int s   = lin & 511;         // row*32 + z
        const int z   = s & 31;
        og[((size_t)fp << 15) + s] = tile[((s >> 5) << 10) + (z << 5) + (fp ^ z)];
    }
}

// ---------------- Fallback: direct-layout global-atomic scatter ----------------
__global__ __launch_bounds__(256) void scatter_kernel(
    const float* __restrict__ vals, const float* __restrict__ keys,
    const float* __restrict__ orig, const float* __restrict__ Rm,
    const float* __restrict__ tv, const float* __restrict__ scale,
    const float* __restrict__ shift, float* __restrict__ out)
{
    const int bid   = blockIdx.x;
    const int g     = bid >> 5;
    const int chunk = bid & 31;
    const int b     = g >> 2;
    const int h     = g & 3;

    __shared__ float sc[32], sh[32], sR[9], st3[3], ksc[3], ksh[3];
    const int t = threadIdx.x;
    if (t < 32)      { sc[t] = scale[12 + h * 32 + t]; sh[t] = shift[12 + h * 32 + t]; }
    else if (t < 41) { sR[t - 32]  = Rm[h * 9 + (t - 32)]; }
    else if (t < 44) { st3[t - 41] = tv[h * 3 + (t - 41)]; }
    else if (t < 47) { ksc[t - 44] = scale[h * 3 + (t - 44)];
                       ksh[t - 44] = shift[h * 3 + (t - 44)]; }
    __syncthreads();

    float* const og = out + ((size_t)g << 20);

    #pragma unroll
    for (int pp = 0; pp < 2; ++pp) {
        const int n = (chunk << 9) + (pp << 8) + t;

        const float k0 = fmaf(keys[(size_t)(g * 3 + 0) * Nn + n], ksc[0], ksh[0]);
        const float k1 = fmaf(keys[(size_t)(g * 3 + 1) * Nn + n], ksc[1], ksh[1]);
        const float k2 = fmaf(keys[(size_t)(g * 3 + 2) * Nn + n], ksc[2], ksh[2]);
        const float p0 = orig[(size_t)(b * 3 + 0) * Nn + n] + k0;
        const float p1 = orig[(size_t)(b * 3 + 1) * Nn + n] + k1;
        const float p2 = orig[(size_t)(b * 3 + 2) * Nn + n] + k2;

        int   idx[3];
        float loc[3];
        #pragma unroll
        for (int d = 0; d < 3; ++d) {
            const float tk = fmaf(sR[d*3+0], p0, fmaf(sR[d*3+1], p1, fmaf(sR[d*3+2], p2, st3[d])));
            const float la = tanhf(tk);
            const float po = (la + 1.f) * 15.5f;
            float fi = floorf(po);
            fi = fminf(fmaxf(fi, 0.f), 30.f);
            idx[d] = (int)fi;
            loc[d] = po - fi;
        }
        const int cell = (idx[0] * Gg + idx[1]) * Gg + idx[2];

        float v[32];
        const float4* vp = reinterpret_cast<const float4*>(vals + ((size_t)g * Nn + n) * Ff);
        #pragma unroll
        for (int q = 0; q < 8; ++q) {
            const float4 xq = vp[q];
            v[4*q+0] = fmaf(xq.x, sc[4*q+0], sh[4*q+0]);
            v[4*q+1] = fmaf(xq.y, sc[4*q+1], sh[4*q+1]);
            v[4*q+2] = fmaf(xq.z, sc[4*q+2], sh[4*q+2]);
            v[4*q+3] = fmaf(xq.w, sc[4*q+3], sh[4*q+3]);
        }

        const float wx1 = loc[0], wx0 = 1.f - loc[0];
        const float wy1 = loc[1], wy0 = 1.f - loc[1];
        const float wz1 = loc[2], wz0 = 1.f - loc[2];
        const float cw[8] = { wx0*wy0*wz0, wx0*wy0*wz1, wx0*wy1*wz0, wx0*wy1*wz1,
                              wx1*wy0*wz0, wx1*wy0*wz1, wx1*wy1*wz0, wx1*wy1*wz1 };
        const int  co[8] = { 0, 1, 32, 33, 1024, 1025, 1056, 1057 };

        #pragma unroll
        for (int ff = 0; ff < 32; ++ff) {
            float* const pf = og + (size_t)ff * G3v + cell;
            const float vf = v[ff];
            #pragma unroll
            for (int c8 = 0; c8 < 8; ++c8) {
                atomicAdd(pf + co[c8], cw[c8] * vf);
            }
        }
    }
}

extern "C" void kernel_launch(void* const* d_in, const int* in_sizes, int n_in,
                              void* d_out, int out_size, void* d_ws, size_t ws_size,
                              hipStream_t stream)
{
    const float* X    = (const float*)d_in[0];
    const float* orig = (const float*)d_in[1];
    const float* W    = (const float*)d_in[2];
    const float* kg   = (const float*)d_in[3];
    const float* kb   = (const float*)d_in[4];
    const float* vg   = (const float*)d_in[5];
    const float* vb   = (const float*)d_in[6];
    const float* Rm   = (const float*)d_in[7];
    const float* tv   = (const float*)d_in[8];
    float* out = (float*)d_out;
    float* ws  = (float*)d_ws;

    // float-offset workspace layout
    float* vals  = ws;                          // 16,777,216
    float* keys  = ws + 16777216;               //  1,572,864
    float* gsum  = ws + 18350080;               // 140
    float* gsq   = gsum + 140;
    float* scale = gsum + 280;
    float* shift = scale + 140;
    int*   cnt    = (int*)(ws + 18350848);      // 953,312
    int*   basep  = (int*)(ws + 19304160);      // 953,312
    int*   cursor = (int*)(ws + 20257472);      // 953,312
    int*   bsum   = (int*)(ws + 21210784);      // 1,024
    int*   bscan  = (int*)(ws + 21211808);      // 1,024
    float4* rec    = (float4*)(ws + 21212832);  // 524,288 float4
    float4* binned = (float4*)(ws + 23309984);  // 524,288 float4
    unsigned short* Wbf = (unsigned short*)(ws + 25407136); // 40,960 bf16
    const size_t need_bytes = (size_t)25427616 * sizeof(float);   // ~101.7 MiB

    hipMemsetAsync(gsum, 0, 280 * sizeof(float), stream);

    prep_w_kernel<<<160, 256, 0, stream>>>(W, Wbf);
    gemm_stats_kernel<<<1024, 256, 0, stream>>>(X, Wbf, vals, keys, gsum, gsq);
    finalize_kernel<<<1, 256, 0, stream>>>(gsum, gsq, kg, kb, vg, vb, scale, shift);

    if (ws_size >= need_bytes) {
        hipMemsetAsync(cnt, 0, (size_t)NB2 * sizeof(int), stream);
        points_kernel<<<2048, 256, 0, stream>>>(keys, orig, Rm, tv, scale, shift, rec, cnt);
        scan1_kernel<<<NCH, 256, 0, stream>>>(cnt, bsum);
        scan2_kernel<<<1, 1024, 0, stream>>>(bsum, bscan);
        scan3_kernel<<<NCH, 256, 0, stream>>>(cnt, bscan, basep, cursor);
        fill_kernel<<<2048, 256, 0, stream>>>(rec, cursor, binned);
        gather_kernel<<<2048, 1024, 0, stream>>>(vals, binned, basep, cnt, scale, shift, out);
    } else {
        hipMemsetAsync(out, 0, (size_t)out_size * sizeof(float), stream);
        scatter_kernel<<<1024, 256, 0, stream>>>(vals, keys, orig, Rm, tv, scale, shift, out);
    }
}

// Round 14
// 291.829 us; speedup vs baseline: 1.0907x; 1.0507x over previous
//
#include <hip/hip_runtime.h>
#include <hip/hip_bf16.h>
#include <cstddef>

#define Bz 8
#define Nn 16384
#define MD 256
#define Ff 32
#define Hh 4
#define Gg 32
#define G3v 32768
#define CKV 140
#define NG 32            // B*H groups
#define NBX 31           // x0 in [0,30]
#define NBY 31           // y0 in [0,30]
#define NBZ 31           // z0 in [0,30]
#define NB2 953312       // NG*NBX*NBY*NBZ
#define NCH 931          // ceil(NB2/1024)

using bf16x8 = __attribute__((ext_vector_type(8))) short;
using f32x16 = __attribute__((ext_vector_type(16))) float;

__device__ __forceinline__ unsigned bf16rne(float f) {
    unsigned u = __float_as_uint(f);
    return (u + 0x7fffu + ((u >> 16) & 1u)) >> 16;
}
__device__ __forceinline__ unsigned cvt2(float lo, float hi) {
    __hip_bfloat162 hb = __float22bfloat162_rn(make_float2(lo, hi));
    union { __hip_bfloat162 b; unsigned u; } c;
    c.b = hb;
    return c.u;
}

// ---------------- Pass 0: W -> bf16, MFMA-fragment order [k>>3][m][k&7], pad m to 160 ----
__global__ __launch_bounds__(256) void prep_w_kernel(const float* __restrict__ W,
                                                     unsigned short* __restrict__ Wbf)
{
    const int idx = blockIdx.x * 256 + threadIdx.x;   // 0..40959
    const int e    = idx & 7;
    const int rest = idx >> 3;
    const int m    = rest % 160;
    const int kg   = rest / 160;
    const int k    = (kg << 3) + e;
    Wbf[idx] = (m < CKV) ? (unsigned short)bf16rne(W[m * MD + k]) : (unsigned short)0;
}

// ---------------- Pass 1: kv = W·X via bf16 MFMA (LDS-staged), fused BN statistics ----------------
__global__ __launch_bounds__(256, 3) void gemm_stats_kernel(
    const float* __restrict__ X, const unsigned short* __restrict__ Wbf,
    float* __restrict__ vals, float* __restrict__ keys,
    float* __restrict__ gsum, float* __restrict__ gsq)
{
    __shared__ unsigned XlU[4096];   // 16 KB  : [k>>3][n][k&7] bf16 pairs
    __shared__ unsigned WlU[5120];   // 20 KB  : dword copy of Wbf K-slice
    __shared__ float red[280];

    const int bid = blockIdx.x;
    const int b   = bid >> 7;
    const int n0  = (bid & 127) << 7;
    const int t   = threadIdx.x;
    const int w   = t >> 6;
    const int ln  = t & 31;
    const int hi  = (t >> 5) & 1;

    f32x16 acc[5];
    #pragma unroll
    for (int mt = 0; mt < 5; ++mt)
        #pragma unroll
        for (int j = 0; j < 16; ++j) acc[mt][j] = 0.f;

    for (int ks = 0; ks < 4; ++ks) {
        const int k0 = ks << 6;
        if (ks > 0) __syncthreads();

        #pragma unroll
        for (int it = 0; it < 4; ++it) {
            const int a  = t + (it << 8);
            const int kp = a >> 5;            // k-pair 0..31 (k = 2kp, 2kp+1)
            const int n4 = (a & 31) << 2;
            const float4 r0 = *reinterpret_cast<const float4*>(
                X + (size_t)(b * MD + k0 + 2 * kp) * Nn + n0 + n4);
            const float4 r1 = *reinterpret_cast<const float4*>(
                X + (size_t)(b * MD + k0 + 2 * kp + 1) * Nn + n0 + n4);
            const int base = ((kp >> 2) << 9) + (n4 << 2) + (kp & 3);
            XlU[base]      = cvt2(r0.x, r1.x);
            XlU[base + 4]  = cvt2(r0.y, r1.y);
            XlU[base + 8]  = cvt2(r0.z, r1.z);
            XlU[base + 12] = cvt2(r0.w, r1.w);
        }
        {
            const unsigned* src = reinterpret_cast<const unsigned*>(Wbf) + ks * 5120;
            #pragma unroll
            for (int i = 0; i < 5; ++i) {
                const int d4 = (t + (i << 8)) << 2;
                *reinterpret_cast<uint4*>(&WlU[d4]) =
                    *reinterpret_cast<const uint4*>(&src[d4]);
            }
        }
        __syncthreads();

        const short* xs = reinterpret_cast<const short*>(XlU);
        const short* ws = reinterpret_cast<const short*>(WlU);
        #pragma unroll
        for (int kk = 0; kk < 4; ++kk) {
            const int grp = (kk << 1) + hi;
            const bf16x8 bf = *reinterpret_cast<const bf16x8*>(
                xs + (((grp << 7) + (w << 5) + ln) << 3));
            #pragma unroll
            for (int mt = 0; mt < 5; ++mt) {
                const bf16x8 af = *reinterpret_cast<const bf16x8*>(
                    ws + ((grp * 160 + (mt << 5) + ln) << 3));
                acc[mt] = __builtin_amdgcn_mfma_f32_32x32x16_bf16(af, bf, acc[mt], 0, 0, 0);
            }
        }
    }

    const int n = n0 + (w << 5) + ln;
    #pragma unroll
    for (int mt = 0; mt < 5; ++mt)
        #pragma unroll
        for (int reg = 0; reg < 16; ++reg) {
            const int ml = (reg & 3) + ((reg >> 2) << 3) + (hi << 2);
            const int c  = mt * 32 + ml;
            const float v = acc[mt][reg];
            if (c < 12) {
                const int hh = c / 3, kk2 = c - (c / 3) * 3;
                keys[(size_t)((b * Hh + hh) * 3 + kk2) * Nn + n] = v;
            } else if (c < CKV) {
                const int cv = c - 12;
                vals[((size_t)(b * Hh + (cv >> 5)) * Nn + n) * Ff + (cv & 31)] = v;
            }
        }

    red[t] = 0.f;
    if (t < 24) red[256 + t] = 0.f;
    __syncthreads();
    #pragma unroll
    for (int mt = 0; mt < 5; ++mt)
        #pragma unroll
        for (int reg = 0; reg < 16; ++reg) {
            if (mt == 4 && reg >= 8) continue;
            const int ml = (reg & 3) + ((reg >> 2) << 3) + (hi << 2);
            const int c  = mt * 32 + ml;
            float s = acc[mt][reg];
            float q = s * s;
            #pragma unroll
            for (int off = 1; off < 32; off <<= 1) {
                s += __shfl_xor(s, off);
                q += __shfl_xor(q, off);
            }
            if (ln == 0 && c < CKV) {
                atomicAdd(&red[c], s);
                atomicAdd(&red[140 + c], q);
            }
        }
    __syncthreads();
    if (t < CKV) {
        atomicAdd(&gsum[t], red[t]);
        atomicAdd(&gsq[t],  red[140 + t]);
    }
}

// ---------------- Pass 2: finalize BN affine params ----------------
__global__ void finalize_kernel(const float* __restrict__ gsum, const float* __restrict__ gsq,
                                const float* __restrict__ kg, const float* __restrict__ kb,
                                const float* __restrict__ vg, const float* __restrict__ vb,
                                float* __restrict__ scale, float* __restrict__ shift)
{
    const int c = threadIdx.x;
    if (c < CKV) {
        const float inv = 1.f / (float)(Bz * Nn);
        const float m = gsum[c] * inv;
        const float v = fmaf(-m, m, gsq[c] * inv);
        float ga, be;
        if (c < 12) { ga = kg[c]; be = kb[c]; }
        else        { ga = vg[c - 12]; be = vb[c - 12]; }
        const float sc = ga * rsqrtf(v + 1e-5f);
        scale[c] = sc;
        shift[c] = fmaf(-m, sc, be);
    }
}

// ---------------- Pass 3a: per-point transform -> record + (g,x0,y0,z0) histogram ----------------
__global__ __launch_bounds__(256) void points_kernel(
    const float* __restrict__ keys, const float* __restrict__ orig,
    const float* __restrict__ Rm, const float* __restrict__ tv,
    const float* __restrict__ scale, const float* __restrict__ shift,
    float4* __restrict__ rec, int* __restrict__ cnt)
{
    const int bid = blockIdx.x;
    const int g   = bid >> 6;
    const int b   = g >> 2;
    const int h   = g & 3;
    const int t   = threadIdx.x;
    const int n   = ((bid & 63) << 8) + t;

    __shared__ float sR[9], st3[3], ksc[3], ksh[3];
    if (t < 9)       sR[t] = Rm[h * 9 + t];
    else if (t < 12) st3[t - 9] = tv[h * 3 + (t - 9)];
    else if (t < 15) { ksc[t - 12] = scale[h * 3 + (t - 12)];
                       ksh[t - 12] = shift[h * 3 + (t - 12)]; }
    __syncthreads();

    const float k0 = fmaf(keys[(size_t)(g * 3 + 0) * Nn + n], ksc[0], ksh[0]);
    const float k1 = fmaf(keys[(size_t)(g * 3 + 1) * Nn + n], ksc[1], ksh[1]);
    const float k2 = fmaf(keys[(size_t)(g * 3 + 2) * Nn + n], ksc[2], ksh[2]);
    const float p0 = orig[(size_t)(b * 3 + 0) * Nn + n] + k0;
    const float p1 = orig[(size_t)(b * 3 + 1) * Nn + n] + k1;
    const float p2 = orig[(size_t)(b * 3 + 2) * Nn + n] + k2;

    int   idx[3];
    float loc[3];
    #pragma unroll
    for (int d = 0; d < 3; ++d) {
        const float tk = fmaf(sR[d*3+0], p0, fmaf(sR[d*3+1], p1, fmaf(sR[d*3+2], p2, st3[d])));
        const float la = tanhf(tk);
        const float po = (la + 1.f) * 15.5f;
        float fi = floorf(po);
        fi = fminf(fmaxf(fi, 0.f), 30.f);
        idx[d] = (int)fi;
        loc[d] = po - fi;
    }

    const unsigned meta = (unsigned)n | ((unsigned)idx[2] << 14) |
                          ((unsigned)idx[1] << 19) | ((unsigned)idx[0] << 24);
    float4 r;
    r.x = __uint_as_float(meta);
    r.y = loc[0]; r.z = loc[1]; r.w = loc[2];
    rec[(size_t)g * Nn + n] = r;
    const int key = ((g * NBX + idx[0]) * NBY + idx[1]) * NBZ + idx[2];
    atomicAdd(&cnt[key], 1);
}

// ---------------- Pass 3b: hierarchical exclusive scan over 953312 bins ----------------
__global__ __launch_bounds__(256) void scan1_kernel(const int* __restrict__ cnt,
                                                    int* __restrict__ bsum)
{
    __shared__ int s[256];
    const int t = threadIdx.x;
    const int i = blockIdx.x * 1024 + t * 4;
    int v = 0;
    #pragma unroll
    for (int j = 0; j < 4; ++j) { const int idx = i + j; if (idx < NB2) v += cnt[idx]; }
    s[t] = v;
    __syncthreads();
    for (int off = 128; off > 0; off >>= 1) {
        if (t < off) s[t] += s[t + off];
        __syncthreads();
    }
    if (t == 0) bsum[blockIdx.x] = s[0];
}

__global__ __launch_bounds__(1024) void scan2_kernel(const int* __restrict__ bsum,
                                                     int* __restrict__ bscan)
{
    __shared__ int s[1024];
    const int t = threadIdx.x;
    const int v = (t < NCH) ? bsum[t] : 0;
    s[t] = v;
    __syncthreads();
    for (int off = 1; off < 1024; off <<= 1) {
        const int x = (t >= off) ? s[t - off] : 0;
        __syncthreads();
        s[t] += x;
        __syncthreads();
    }
    if (t < NCH) bscan[t] = s[t] - v;   // exclusive
}

__global__ __launch_bounds__(256) void scan3_kernel(const int* __restrict__ cnt,
                                                    const int* __restrict__ bscan,
                                                    int* __restrict__ basep,
                                                    int* __restrict__ cursor)
{
    __shared__ int s[256];
    const int t = threadIdx.x;
    const int i = blockIdx.x * 1024 + t * 4;
    int c[4], l[4];
    int sum = 0;
    #pragma unroll
    for (int j = 0; j < 4; ++j) {
        const int idx = i + j;
        c[j] = (idx < NB2) ? cnt[idx] : 0;
        l[j] = sum; sum += c[j];
    }
    s[t] = sum;
    __syncthreads();
    for (int off = 1; off < 256; off <<= 1) {
        const int x = (t >= off) ? s[t - off] : 0;
        __syncthreads();
        s[t] += x;
        __syncthreads();
    }
    const int off0 = bscan[blockIdx.x] + s[t] - sum;
    #pragma unroll
    for (int j = 0; j < 4; ++j) {
        const int idx = i + j;
        if (idx < NB2) { basep[idx] = off0 + l[j]; cursor[idx] = off0 + l[j]; }
    }
}

// ---------------- Pass 3c: counting-sort records into (g,x0,y0,z0) bins ----------------
__global__ __launch_bounds__(256) void fill_kernel(
    const float4* __restrict__ rec, int* __restrict__ cursor,
    float4* __restrict__ binned)
{
    const int bid = blockIdx.x;
    const int g   = bid >> 6;
    const int t   = threadIdx.x;
    const int n   = ((bid & 63) << 8) + t;
    const float4 r = rec[(size_t)g * Nn + n];
    const unsigned meta = __float_as_uint(r.x);
    const int x0 = (meta >> 24) & 31;
    const int y0 = (meta >> 19) & 31;
    const int z0 = (meta >> 14) & 31;
    const int key = ((g * NBX + x0) * NBY + y0) * NBZ + z0;
    const int pos = atomicAdd(&cursor[key], 1);
    binned[pos] = r;
}

// ---------------- Pass 3d: gather via MFMA outer products ----------------
// Grid: 2048 blocks = g | x<<5 | yh<<10; 1024 threads = 16 waves; wave w owns row y.
// 16-record chunk = one mfma_f32_32x32x16_bf16: A[z][k] = trilinear weight (2 nz/col),
// B[k][f] = BN'd value. acc[16] = wave's 32z x 32f output tile; LDS only for transpose.
#define MKAB(qe, ridx, ae, ve)                                               \
{                                                                            \
    const unsigned mq = __float_as_uint((qe).x);                             \
    const int z0 = (int)((mq >> 14) & 31u);                                  \
    const float wx  = dx ? (1.f - (qe).y) : (qe).y;                          \
    const float wy  = dy ? (1.f - (qe).z) : (qe).z;                          \
    const float wxy = ((ridx) < e) ? wx * wy : 0.f;                          \
    const float lz  = (qe).w;                                                \
    ae = (ln == z0) ? (1.f - lz) * wxy                                       \
                    : ((ln == z0 + 1) ? lz * wxy : 0.f);                     \
    ve = fmaf(vg[(((size_t)(mq & 16383u)) << 5) + ln], scf, shf);            \
}

__global__ __launch_bounds__(1024) void gather_kernel(
    const float* __restrict__ vals, const float4* __restrict__ binned,
    const int* __restrict__ basep, const int* __restrict__ cnt,
    const float* __restrict__ scale, const float* __restrict__ shift,
    float* __restrict__ out)
{
    __shared__ float tile[16384];
    __shared__ float sscale[32], sshift[32];

    const int bid = blockIdx.x;
    const int g   = bid & 31;
    const int x   = (bid >> 5) & 31;
    const int yh  = bid >> 10;
    const int h   = g & 3;
    const int t   = threadIdx.x;

    if (t < 32) { sscale[t] = scale[12 + h * 32 + t]; sshift[t] = shift[12 + h * 32 + t]; }
    __syncthreads();

    const int ln = t & 31;            // A row (z) / B col (f)
    const int hi = (t >> 5) & 1;      // k-octet select
    const int w  = t >> 6;            // wave id 0..15
    const int y  = (yh << 4) + w;     // owned output row
    const float scf = sscale[ln], shf = sshift[ln];
    const float* vg = vals + ((size_t)g << 19);   // g * Nn * Ff

    f32x16 acc;
    #pragma unroll
    for (int j = 0; j < 16; ++j) acc[j] = 0.f;

    #pragma unroll
    for (int dy = 0; dy < 2; ++dy) {
        const int y0 = y - 1 + dy;                // dy=0: wy=q.z ; dy=1: wy=1-q.z
        if ((unsigned)y0 > 30u) continue;
        #pragma unroll
        for (int dx = 0; dx < 2; ++dx) {
            const int x0 = x - 1 + dx;
            if ((unsigned)x0 > 30u) continue;
            const int kb = ((g * NBX + x0) * NBY + y0) * NBZ;
            int r       = basep[kb];
            const int e = basep[kb + 30] + cnt[kb + 30];

            for (; r < e; r += 16) {
                const int base = r + (hi << 3);
                const int eM1  = e - 1;
                const int r0 = min(base,     eM1);
                const int r1 = min(base + 1, eM1);
                const int r2 = min(base + 2, eM1);
                const int r3 = min(base + 3, eM1);
                const int r4 = min(base + 4, eM1);
                const int r5 = min(base + 5, eM1);
                const int r6 = min(base + 6, eM1);
                const int r7 = min(base + 7, eM1);
                const float4 q0 = binned[r0];
                const float4 q1 = binned[r1];
                const float4 q2 = binned[r2];
                const float4 q3 = binned[r3];
                const float4 q4 = binned[r4];
                const float4 q5 = binned[r5];
                const float4 q6 = binned[r6];
                const float4 q7 = binned[r7];
                float a0, a1, a2, a3, a4, a5, a6, a7;
                float v0, v1, v2, v3, v4, v5, v6, v7;
                MKAB(q0, base,     a0, v0);
                MKAB(q1, base + 1, a1, v1);
                MKAB(q2, base + 2, a2, v2);
                MKAB(q3, base + 3, a3, v3);
                MKAB(q4, base + 4, a4, v4);
                MKAB(q5, base + 5, a5, v5);
                MKAB(q6, base + 6, a6, v6);
                MKAB(q7, base + 7, a7, v7);
                union { bf16x8 v; unsigned u[4]; } af, bf;
                af.u[0] = cvt2(a0, a1); af.u[1] = cvt2(a2, a3);
                af.u[2] = cvt2(a4, a5); af.u[3] = cvt2(a6, a7);
                bf.u[0] = cvt2(v0, v1); bf.u[1] = cvt2(v2, v3);
                bf.u[2] = cvt2(v4, v5); bf.u[3] = cvt2(v6, v7);
                acc = __builtin_amdgcn_mfma_f32_32x32x16_bf16(af.v, bf.v, acc, 0, 0, 0);
            }
        }
    }

    // write acc -> wave tile: C[row=z][col=f], stored swizzled [z][f^z]
    float* const tg = &tile[w << 10];
    #pragma unroll
    for (int reg = 0; reg < 16; ++reg) {
        const int zr = (reg & 3) + ((reg >> 2) << 3) + (hi << 2);
        tg[(zr << 5) + ((ln ^ zr) & 31)] = acc[reg];
    }
    __syncthreads();

    // write out[(g*32+fp)*G3 + x*1024 + yh*512 + row*32 + z]
    float* og = out + ((size_t)g << 20) + (x << 10) + (yh << 9);
    #pragma unroll
    for (int i = 0; i < 16; ++i) {
        const int lin = t + (i << 10);
        const int fp  = lin >> 9;          // 0..31
        const int s   = lin & 511;         // row*32 + z
        const int z   = s & 31;
        og[((size_t)fp << 15) + s] = tile[((s >> 5) << 10) + (z << 5) + ((fp ^ z) & 31)];
    }
}

// ---------------- Fallback: direct-layout global-atomic scatter ----------------
__global__ __launch_bounds__(256) void scatter_kernel(
    const float* __restrict__ vals, const float* __restrict__ keys,
    const float* __restrict__ orig, const float* __restrict__ Rm,
    const float* __restrict__ tv, const float* __restrict__ scale,
    const float* __restrict__ shift, float* __restrict__ out)
{
    const int bid   = blockIdx.x;
    const int g     = bid >> 5;
    const int chunk = bid & 31;
    const int b     = g >> 2;
    const int h     = g & 3;

    __shared__ float sc[32], sh[32], sR[9], st3[3], ksc[3], ksh[3];
    const int t = threadIdx.x;
    if (t < 32)      { sc[t] = scale[12 + h * 32 + t]; sh[t] = shift[12 + h * 32 + t]; }
    else if (t < 41) { sR[t - 32]  = Rm[h * 9 + (t - 32)]; }
    else if (t < 44) { st3[t - 41] = tv[h * 3 + (t - 41)]; }
    else if (t < 47) { ksc[t - 44] = scale[h * 3 + (t - 44)];
                       ksh[t - 44] = shift[h * 3 + (t - 44)]; }
    __syncthreads();

    float* const og = out + ((size_t)g << 20);

    #pragma unroll
    for (int pp = 0; pp < 2; ++pp) {
        const int n = (chunk << 9) + (pp << 8) + t;

        const float k0 = fmaf(keys[(size_t)(g * 3 + 0) * Nn + n], ksc[0], ksh[0]);
        const float k1 = fmaf(keys[(size_t)(g * 3 + 1) * Nn + n], ksc[1], ksh[1]);
        const float k2 = fmaf(keys[(size_t)(g * 3 + 2) * Nn + n], ksc[2], ksh[2]);
        const float p0 = orig[(size_t)(b * 3 + 0) * Nn + n] + k0;
        const float p1 = orig[(size_t)(b * 3 + 1) * Nn + n] + k1;
        const float p2 = orig[(size_t)(b * 3 + 2) * Nn + n] + k2;

        int   idx[3];
        float loc[3];
        #pragma unroll
        for (int d = 0; d < 3; ++d) {
            const float tk = fmaf(sR[d*3+0], p0, fmaf(sR[d*3+1], p1, fmaf(sR[d*3+2], p2, st3[d])));
            const float la = tanhf(tk);
            const float po = (la + 1.f) * 15.5f;
            float fi = floorf(po);
            fi = fminf(fmaxf(fi, 0.f), 30.f);
            idx[d] = (int)fi;
            loc[d] = po - fi;
        }
        const int cell = (idx[0] * Gg + idx[1]) * Gg + idx[2];

        float v[32];
        const float4* vp = reinterpret_cast<const float4*>(vals + ((size_t)g * Nn + n) * Ff);
        #pragma unroll
        for (int q = 0; q < 8; ++q) {
            const float4 xq = vp[q];
            v[4*q+0] = fmaf(xq.x, sc[4*q+0], sh[4*q+0]);
            v[4*q+1] = fmaf(xq.y, sc[4*q+1], sh[4*q+1]);
            v[4*q+2] = fmaf(xq.z, sc[4*q+2], sh[4*q+2]);
            v[4*q+3] = fmaf(xq.w, sc[4*q+3], sh[4*q+3]);
        }

        const float wx1 = loc[0], wx0 = 1.f - loc[0];
        const float wy1 = loc[1], wy0 = 1.f - loc[1];
        const float wz1 = loc[2], wz0 = 1.f - loc[2];
        const float cw[8] = { wx0*wy0*wz0, wx0*wy0*wz1, wx0*wy1*wz0, wx0*wy1*wz1,
                              wx1*wy0*wz0, wx1*wy0*wz1, wx1*wy1*wz0, wx1*wy1*wz1 };
        const int  co[8] = { 0, 1, 32, 33, 1024, 1025, 1056, 1057 };

        #pragma unroll
        for (int ff = 0; ff < 32; ++ff) {
            float* const pf = og + (size_t)ff * G3v + cell;
            const float vf = v[ff];
            #pragma unroll
            for (int c8 = 0; c8 < 8; ++c8) {
                atomicAdd(pf + co[c8], cw[c8] * vf);
            }
        }
    }
}

extern "C" void kernel_launch(void* const* d_in, const int* in_sizes, int n_in,
                              void* d_out, int out_size, void* d_ws, size_t ws_size,
                              hipStream_t stream)
{
    const float* X    = (const float*)d_in[0];
    const float* orig = (const float*)d_in[1];
    const float* W    = (const float*)d_in[2];
    const float* kg   = (const float*)d_in[3];
    const float* kb   = (const float*)d_in[4];
    const float* vg   = (const float*)d_in[5];
    const float* vb   = (const float*)d_in[6];
    const float* Rm   = (const float*)d_in[7];
    const float* tv   = (const float*)d_in[8];
    float* out = (float*)d_out;
    float* ws  = (float*)d_ws;

    // float-offset workspace layout
    float* vals  = ws;                          // 16,777,216
    float* keys  = ws + 16777216;               //  1,572,864
    float* gsum  = ws + 18350080;               // 140
    float* gsq   = gsum + 140;
    float* scale = gsum + 280;
    float* shift = scale + 140;
    int*   cnt    = (int*)(ws + 18350848);      // 953,312
    int*   basep  = (int*)(ws + 19304160);      // 953,312
    int*   cursor = (int*)(ws + 20257472);      // 953,312
    int*   bsum   = (int*)(ws + 21210784);      // 1,024
    int*   bscan  = (int*)(ws + 21211808);      // 1,024
    float4* rec    = (float4*)(ws + 21212832);  // 524,288 float4
    float4* binned = (float4*)(ws + 23309984);  // 524,288 float4
    unsigned short* Wbf = (unsigned short*)(ws + 25407136); // 40,960 bf16
    const size_t need_bytes = (size_t)25427616 * sizeof(float);   // ~101.7 MiB

    hipMemsetAsync(gsum, 0, 280 * sizeof(float), stream);

    prep_w_kernel<<<160, 256, 0, stream>>>(W, Wbf);
    gemm_stats_kernel<<<1024, 256, 0, stream>>>(X, Wbf, vals, keys, gsum, gsq);
    finalize_kernel<<<1, 256, 0, stream>>>(gsum, gsq, kg, kb, vg, vb, scale, shift);

    if (ws_size >= need_bytes) {
        hipMemsetAsync(cnt, 0, (size_t)NB2 * sizeof(int), stream);
        points_kernel<<<2048, 256, 0, stream>>>(keys, orig, Rm, tv, scale, shift, rec, cnt);
        scan1_kernel<<<NCH, 256, 0, stream>>>(cnt, bsum);
        scan2_kernel<<<1, 1024, 0, stream>>>(bsum, bscan);
        scan3_kernel<<<NCH, 256, 0, stream>>>(cnt, bscan, basep, cursor);
        fill_kernel<<<2048, 256, 0, stream>>>(rec, cursor, binned);
        gather_kernel<<<2048, 1024, 0, stream>>>(vals, binned, basep, cnt, scale, shift, out);
    } else {
        hipMemsetAsync(out, 0, (size_t)out_size * sizeof(float), stream);
        scatter_kernel<<<1024, 256, 0, stream>>>(vals, keys, orig, Rm, tv, scale, shift, out);
    }
}

// Round 15
// 286.539 us; speedup vs baseline: 1.1108x; 1.0185x over previous
//
#include <hip/hip_runtime.h>
#include <hip/hip_bf16.h>
#include <cstddef>

#define Bz 8
#define Nn 16384
#define MD 256
#define Ff 32
#define Hh 4
#define Gg 32
#define G3v 32768
#define CKV 140
#define NG 32            // B*H groups
#define NBX 31           // x0 in [0,30]
#define NBY 31           // y0 in [0,30]
#define NBZ 31           // z0 in [0,30]
#define NB2 953312       // NG*NBX*NBY*NBZ
#define NCH 931          // ceil(NB2/1024)

using bf16x8 = __attribute__((ext_vector_type(8))) short;
using f32x16 = __attribute__((ext_vector_type(16))) float;

__device__ __forceinline__ unsigned bf16rne(float f) {
    unsigned u = __float_as_uint(f);
    return (u + 0x7fffu + ((u >> 16) & 1u)) >> 16;
}
__device__ __forceinline__ unsigned cvt2(float lo, float hi) {
    __hip_bfloat162 hb = __float22bfloat162_rn(make_float2(lo, hi));
    union { __hip_bfloat162 b; unsigned u; } c;
    c.b = hb;
    return c.u;
}

// ---------------- Pass 0: W -> bf16, MFMA-fragment order [k>>3][m][k&7], pad m to 160 ----
__global__ __launch_bounds__(256) void prep_w_kernel(const float* __restrict__ W,
                                                     unsigned short* __restrict__ Wbf)
{
    const int idx = blockIdx.x * 256 + threadIdx.x;   // 0..40959
    const int e    = idx & 7;
    const int rest = idx >> 3;
    const int m    = rest % 160;
    const int kg   = rest / 160;
    const int k    = (kg << 3) + e;
    Wbf[idx] = (m < CKV) ? (unsigned short)bf16rne(W[m * MD + k]) : (unsigned short)0;
}

// ---------------- Pass 1: kv = W·X via bf16 MFMA (LDS-staged), fused BN statistics ----------------
// Post-loop: per-mt LDS transpose -> coalesced float4 vals stores (keys stored direct).
__global__ __launch_bounds__(256, 3) void gemm_stats_kernel(
    const float* __restrict__ X, const unsigned short* __restrict__ Wbf,
    float* __restrict__ vals, float* __restrict__ keys,
    float* __restrict__ gsum, float* __restrict__ gsq)
{
    __shared__ float smem[9216];     // 36 KB: staging (XlU 4096 dw | WlU 5120 dw), then [128 n][36] transpose
    __shared__ float red[280];
    unsigned* XlU = reinterpret_cast<unsigned*>(smem);
    unsigned* WlU = reinterpret_cast<unsigned*>(smem) + 4096;

    const int bid = blockIdx.x;
    const int b   = bid >> 7;
    const int n0  = (bid & 127) << 7;
    const int t   = threadIdx.x;
    const int w   = t >> 6;
    const int ln  = t & 31;
    const int hi  = (t >> 5) & 1;

    f32x16 acc[5];
    #pragma unroll
    for (int mt = 0; mt < 5; ++mt)
        #pragma unroll
        for (int j = 0; j < 16; ++j) acc[mt][j] = 0.f;

    for (int ks = 0; ks < 4; ++ks) {
        const int k0 = ks << 6;
        if (ks > 0) __syncthreads();

        #pragma unroll
        for (int it = 0; it < 4; ++it) {
            const int a  = t + (it << 8);
            const int kp = a >> 5;            // k-pair 0..31 (k = 2kp, 2kp+1)
            const int n4 = (a & 31) << 2;
            const float4 r0 = *reinterpret_cast<const float4*>(
                X + (size_t)(b * MD + k0 + 2 * kp) * Nn + n0 + n4);
            const float4 r1 = *reinterpret_cast<const float4*>(
                X + (size_t)(b * MD + k0 + 2 * kp + 1) * Nn + n0 + n4);
            const int base = ((kp >> 2) << 9) + (n4 << 2) + (kp & 3);
            XlU[base]      = cvt2(r0.x, r1.x);
            XlU[base + 4]  = cvt2(r0.y, r1.y);
            XlU[base + 8]  = cvt2(r0.z, r1.z);
            XlU[base + 12] = cvt2(r0.w, r1.w);
        }
        {
            const unsigned* src = reinterpret_cast<const unsigned*>(Wbf) + ks * 5120;
            #pragma unroll
            for (int i = 0; i < 5; ++i) {
                const int d4 = (t + (i << 8)) << 2;
                *reinterpret_cast<uint4*>(&WlU[d4]) =
                    *reinterpret_cast<const uint4*>(&src[d4]);
            }
        }
        __syncthreads();

        const short* xs = reinterpret_cast<const short*>(XlU);
        const short* ws = reinterpret_cast<const short*>(WlU);
        #pragma unroll
        for (int kk = 0; kk < 4; ++kk) {
            const int grp = (kk << 1) + hi;
            const bf16x8 bf = *reinterpret_cast<const bf16x8*>(
                xs + (((grp << 7) + (w << 5) + ln) << 3));
            #pragma unroll
            for (int mt = 0; mt < 5; ++mt) {
                const bf16x8 af = *reinterpret_cast<const bf16x8*>(
                    ws + ((grp * 160 + (mt << 5) + ln) << 3));
                acc[mt] = __builtin_amdgcn_mfma_f32_32x32x16_bf16(af, bf, acc[mt], 0, 0, 0);
            }
        }
    }

    // ---- keys direct store (c<12): lanes contiguous in n -> already coalesced ----
    const int n = n0 + (w << 5) + ln;
    #pragma unroll
    for (int reg = 0; reg < 8; ++reg) {
        const int ml = (reg & 3) + ((reg >> 2) << 3) + (hi << 2);
        if (ml < 12) {
            const int hh = ml / 3, kk2 = ml - (ml / 3) * 3;
            keys[(size_t)((b * Hh + hh) * 3 + kk2) * Nn + n] = acc[0][reg];
        }
    }

    // ---- vals: per-mt LDS transpose -> coalesced float4 stores along f ----
    const int nl = (w << 5) + ln;     // block-local column 0..127
    #pragma unroll
    for (int mt = 0; mt < 5; ++mt) {
        __syncthreads();
        #pragma unroll
        for (int reg = 0; reg < 16; ++reg) {
            const int ml = (reg & 3) + ((reg >> 2) << 3) + (hi << 2);
            smem[nl * 36 + ml] = acc[mt][reg];
        }
        __syncthreads();
        #pragma unroll
        for (int i = 0; i < 4; ++i) {
            const int id = t + (i << 8);
            const int nn = id >> 3;           // 0..127
            const int q  = id & 7;            // channel quad within mt tile
            const int c  = (mt << 5) + (q << 2);
            if (c < 12 || c >= CKV) continue;
            const int cv = c - 12;
            const float4 v4 = *reinterpret_cast<const float4*>(&smem[nn * 36 + (q << 2)]);
            *reinterpret_cast<float4*>(
                &vals[((size_t)(b * Hh + (cv >> 5)) * Nn + n0 + nn) * Ff + (cv & 31)]) = v4;
        }
    }

    // ---- BN statistics: 32-lane shuffle reduce over n, then LDS + global atomics ----
    red[t] = 0.f;
    if (t < 24) red[256 + t] = 0.f;
    __syncthreads();
    #pragma unroll
    for (int mt = 0; mt < 5; ++mt)
        #pragma unroll
        for (int reg = 0; reg < 16; ++reg) {
            if (mt == 4 && reg >= 8) continue;
            const int ml = (reg & 3) + ((reg >> 2) << 3) + (hi << 2);
            const int c  = mt * 32 + ml;
            float s = acc[mt][reg];
            float q = s * s;
            #pragma unroll
            for (int off = 1; off < 32; off <<= 1) {
                s += __shfl_xor(s, off);
                q += __shfl_xor(q, off);
            }
            if (ln == 0 && c < CKV) {
                atomicAdd(&red[c], s);
                atomicAdd(&red[140 + c], q);
            }
        }
    __syncthreads();
    if (t < CKV) {
        atomicAdd(&gsum[t], red[t]);
        atomicAdd(&gsq[t],  red[140 + t]);
    }
}

// ---------------- Pass 2: finalize BN affine params ----------------
__global__ void finalize_kernel(const float* __restrict__ gsum, const float* __restrict__ gsq,
                                const float* __restrict__ kg, const float* __restrict__ kb,
                                const float* __restrict__ vg, const float* __restrict__ vb,
                                float* __restrict__ scale, float* __restrict__ shift)
{
    const int c = threadIdx.x;
    if (c < CKV) {
        const float inv = 1.f / (float)(Bz * Nn);
        const float m = gsum[c] * inv;
        const float v = fmaf(-m, m, gsq[c] * inv);
        float ga, be;
        if (c < 12) { ga = kg[c]; be = kb[c]; }
        else        { ga = vg[c - 12]; be = vb[c - 12]; }
        const float sc = ga * rsqrtf(v + 1e-5f);
        scale[c] = sc;
        shift[c] = fmaf(-m, sc, be);
    }
}

// ---------------- Pass 3a: per-point transform -> record + (g,x0,y0,z0) histogram ----------------
__global__ __launch_bounds__(256) void points_kernel(
    const float* __restrict__ keys, const float* __restrict__ orig,
    const float* __restrict__ Rm, const float* __restrict__ tv,
    const float* __restrict__ scale, const float* __restrict__ shift,
    float4* __restrict__ rec, int* __restrict__ cnt)
{
    const int bid = blockIdx.x;
    const int g   = bid >> 6;
    const int b   = g >> 2;
    const int h   = g & 3;
    const int t   = threadIdx.x;
    const int n   = ((bid & 63) << 8) + t;

    __shared__ float sR[9], st3[3], ksc[3], ksh[3];
    if (t < 9)       sR[t] = Rm[h * 9 + t];
    else if (t < 12) st3[t - 9] = tv[h * 3 + (t - 9)];
    else if (t < 15) { ksc[t - 12] = scale[h * 3 + (t - 12)];
                       ksh[t - 12] = shift[h * 3 + (t - 12)]; }
    __syncthreads();

    const float k0 = fmaf(keys[(size_t)(g * 3 + 0) * Nn + n], ksc[0], ksh[0]);
    const float k1 = fmaf(keys[(size_t)(g * 3 + 1) * Nn + n], ksc[1], ksh[1]);
    const float k2 = fmaf(keys[(size_t)(g * 3 + 2) * Nn + n], ksc[2], ksh[2]);
    const float p0 = orig[(size_t)(b * 3 + 0) * Nn + n] + k0;
    const float p1 = orig[(size_t)(b * 3 + 1) * Nn + n] + k1;
    const float p2 = orig[(size_t)(b * 3 + 2) * Nn + n] + k2;

    int   idx[3];
    float loc[3];
    #pragma unroll
    for (int d = 0; d < 3; ++d) {
        const float tk = fmaf(sR[d*3+0], p0, fmaf(sR[d*3+1], p1, fmaf(sR[d*3+2], p2, st3[d])));
        const float la = tanhf(tk);
        const float po = (la + 1.f) * 15.5f;
        float fi = floorf(po);
        fi = fminf(fmaxf(fi, 0.f), 30.f);
        idx[d] = (int)fi;
        loc[d] = po - fi;
    }

    const unsigned meta = (unsigned)n | ((unsigned)idx[2] << 14) |
                          ((unsigned)idx[1] << 19) | ((unsigned)idx[0] << 24);
    float4 r;
    r.x = __uint_as_float(meta);
    r.y = loc[0]; r.z = loc[1]; r.w = loc[2];
    rec[(size_t)g * Nn + n] = r;
    const int key = ((g * NBX + idx[0]) * NBY + idx[1]) * NBZ + idx[2];
    atomicAdd(&cnt[key], 1);
}

// ---------------- Pass 3b: hierarchical exclusive scan over 953312 bins ----------------
__global__ __launch_bounds__(256) void scan1_kernel(const int* __restrict__ cnt,
                                                    int* __restrict__ bsum)
{
    __shared__ int s[256];
    const int t = threadIdx.x;
    const int i = blockIdx.x * 1024 + t * 4;
    int v = 0;
    #pragma unroll
    for (int j = 0; j < 4; ++j) { const int idx = i + j; if (idx < NB2) v += cnt[idx]; }
    s[t] = v;
    __syncthreads();
    for (int off = 128; off > 0; off >>= 1) {
        if (t < off) s[t] += s[t + off];
        __syncthreads();
    }
    if (t == 0) bsum[blockIdx.x] = s[0];
}

__global__ __launch_bounds__(1024) void scan2_kernel(const int* __restrict__ bsum,
                                                     int* __restrict__ bscan)
{
    __shared__ int s[1024];
    const int t = threadIdx.x;
    const int v = (t < NCH) ? bsum[t] : 0;
    s[t] = v;
    __syncthreads();
    for (int off = 1; off < 1024; off <<= 1) {
        const int x = (t >= off) ? s[t - off] : 0;
        __syncthreads();
        s[t] += x;
        __syncthreads();
    }
    if (t < NCH) bscan[t] = s[t] - v;   // exclusive
}

__global__ __launch_bounds__(256) void scan3_kernel(const int* __restrict__ cnt,
                                                    const int* __restrict__ bscan,
                                                    int* __restrict__ basep,
                                                    int* __restrict__ cursor)
{
    __shared__ int s[256];
    const int t = threadIdx.x;
    const int i = blockIdx.x * 1024 + t * 4;
    int c[4], l[4];
    int sum = 0;
    #pragma unroll
    for (int j = 0; j < 4; ++j) {
        const int idx = i + j;
        c[j] = (idx < NB2) ? cnt[idx] : 0;
        l[j] = sum; sum += c[j];
    }
    s[t] = sum;
    __syncthreads();
    for (int off = 1; off < 256; off <<= 1) {
        const int x = (t >= off) ? s[t - off] : 0;
        __syncthreads();
        s[t] += x;
        __syncthreads();
    }
    const int off0 = bscan[blockIdx.x] + s[t] - sum;
    #pragma unroll
    for (int j = 0; j < 4; ++j) {
        const int idx = i + j;
        if (idx < NB2) { basep[idx] = off0 + l[j]; cursor[idx] = off0 + l[j]; }
    }
}

// ---------------- Pass 3c: counting-sort records into (g,x0,y0,z0) bins ----------------
__global__ __launch_bounds__(256) void fill_kernel(
    const float4* __restrict__ rec, int* __restrict__ cursor,
    float4* __restrict__ binned)
{
    const int bid = blockIdx.x;
    const int g   = bid >> 6;
    const int t   = threadIdx.x;
    const int n   = ((bid & 63) << 8) + t;
    const float4 r = rec[(size_t)g * Nn + n];
    const unsigned meta = __float_as_uint(r.x);
    const int x0 = (meta >> 24) & 31;
    const int y0 = (meta >> 19) & 31;
    const int z0 = (meta >> 14) & 31;
    const int key = ((g * NBX + x0) * NBY + y0) * NBZ + z0;
    const int pos = atomicAdd(&cursor[key], 1);
    binned[pos] = r;
}

// ---------------- Pass 3d: gather via MFMA outer products ----------------
#define MKAB(qe, ridx, ae, ve)                                               \
{                                                                            \
    const unsigned mq = __float_as_uint((qe).x);                             \
    const int z0 = (int)((mq >> 14) & 31u);                                  \
    const float wx  = dx ? (1.f - (qe).y) : (qe).y;                          \
    const float wy  = dy ? (1.f - (qe).z) : (qe).z;                          \
    const float wxy = ((ridx) < e) ? wx * wy : 0.f;                          \
    const float lz  = (qe).w;                                                \
    ae = (ln == z0) ? (1.f - lz) * wxy                                       \
                    : ((ln == z0 + 1) ? lz * wxy : 0.f);                     \
    ve = fmaf(vg[(((size_t)(mq & 16383u)) << 5) + ln], scf, shf);            \
}

__global__ __launch_bounds__(1024) void gather_kernel(
    const float* __restrict__ vals, const float4* __restrict__ binned,
    const int* __restrict__ basep, const int* __restrict__ cnt,
    const float* __restrict__ scale, const float* __restrict__ shift,
    float* __restrict__ out)
{
    __shared__ float tile[16384];
    __shared__ float sscale[32], sshift[32];

    const int bid = blockIdx.x;
    const int g   = bid & 31;
    const int x   = (bid >> 5) & 31;
    const int yh  = bid >> 10;
    const int h   = g & 3;
    const int t   = threadIdx.x;

    if (t < 32) { sscale[t] = scale[12 + h * 32 + t]; sshift[t] = shift[12 + h * 32 + t]; }
    __syncthreads();

    const int ln = t & 31;            // A row (z) / B col (f)
    const int hi = (t >> 5) & 1;      // k-octet select
    const int w  = t >> 6;            // wave id 0..15
    const int y  = (yh << 4) + w;     // owned output row
    const float scf = sscale[ln], shf = sshift[ln];
    const float* vg = vals + ((size_t)g << 19);   // g * Nn * Ff

    f32x16 acc;
    #pragma unroll
    for (int j = 0; j < 16; ++j) acc[j] = 0.f;

    #pragma unroll
    for (int dy = 0; dy < 2; ++dy) {
        const int y0 = y - 1 + dy;                // dy=0: wy=q.z ; dy=1: wy=1-q.z
        if ((unsigned)y0 > 30u) continue;
        #pragma unroll
        for (int dx = 0; dx < 2; ++dx) {
            const int x0 = x - 1 + dx;
            if ((unsigned)x0 > 30u) continue;
            const int kb = ((g * NBX + x0) * NBY + y0) * NBZ;
            int r       = basep[kb];
            const int e = basep[kb + 30] + cnt[kb + 30];

            for (; r < e; r += 16) {
                const int base = r + (hi << 3);
                const int eM1  = e - 1;
                const int r0 = min(base,     eM1);
                const int r1 = min(base + 1, eM1);
                const int r2 = min(base + 2, eM1);
                const int r3 = min(base + 3, eM1);
                const int r4 = min(base + 4, eM1);
                const int r5 = min(base + 5, eM1);
                const int r6 = min(base + 6, eM1);
                const int r7 = min(base + 7, eM1);
                const float4 q0 = binned[r0];
                const float4 q1 = binned[r1];
                const float4 q2 = binned[r2];
                const float4 q3 = binned[r3];
                const float4 q4 = binned[r4];
                const float4 q5 = binned[r5];
                const float4 q6 = binned[r6];
                const float4 q7 = binned[r7];
                float a0, a1, a2, a3, a4, a5, a6, a7;
                float v0, v1, v2, v3, v4, v5, v6, v7;
                MKAB(q0, base,     a0, v0);
                MKAB(q1, base + 1, a1, v1);
                MKAB(q2, base + 2, a2, v2);
                MKAB(q3, base + 3, a3, v3);
                MKAB(q4, base + 4, a4, v4);
                MKAB(q5, base + 5, a5, v5);
                MKAB(q6, base + 6, a6, v6);
                MKAB(q7, base + 7, a7, v7);
                union { bf16x8 v; unsigned u[4]; } af, bf;
                af.u[0] = cvt2(a0, a1); af.u[1] = cvt2(a2, a3);
                af.u[2] = cvt2(a4, a5); af.u[3] = cvt2(a6, a7);
                bf.u[0] = cvt2(v0, v1); bf.u[1] = cvt2(v2, v3);
                bf.u[2] = cvt2(v4, v5); bf.u[3] = cvt2(v6, v7);
                acc = __builtin_amdgcn_mfma_f32_32x32x16_bf16(af.v, bf.v, acc, 0, 0, 0);
            }
        }
    }

    // write acc -> wave tile: C[row=z][col=f], stored swizzled [z][f^z]
    float* const tg = &tile[w << 10];
    #pragma unroll
    for (int reg = 0; reg < 16; ++reg) {
        const int zr = (reg & 3) + ((reg >> 2) << 3) + (hi << 2);
        tg[(zr << 5) + ((ln ^ zr) & 31)] = acc[reg];
    }
    __syncthreads();

    // write out[(g*32+fp)*G3 + x*1024 + yh*512 + row*32 + z]
    float* og = out + ((size_t)g << 20) + (x << 10) + (yh << 9);
    #pragma unroll
    for (int i = 0; i < 16; ++i) {
        const int lin = t + (i << 10);
        const int fp  = lin >> 9;          // 0..31
        const int s   = lin & 511;         // row*32 + z
        const int z   = s & 31;
        og[((size_t)fp << 15) + s] = tile[((s >> 5) << 10) + (z << 5) + ((fp ^ z) & 31)];
    }
}

// ---------------- Fallback: direct-layout global-atomic scatter ----------------
__global__ __launch_bounds__(256) void scatter_kernel(
    const float* __restrict__ vals, const float* __restrict__ keys,
    const float* __restrict__ orig, const float* __restrict__ Rm,
    const float* __restrict__ tv, const float* __restrict__ scale,
    const float* __restrict__ shift, float* __restrict__ out)
{
    const int bid   = blockIdx.x;
    const int g     = bid >> 5;
    const int chunk = bid & 31;
    const int b     = g >> 2;
    const int h     = g & 3;

    __shared__ float sc[32], sh[32], sR[9], st3[3], ksc[3], ksh[3];
    const int t = threadIdx.x;
    if (t < 32)      { sc[t] = scale[12 + h * 32 + t]; sh[t] = shift[12 + h * 32 + t]; }
    else if (t < 41) { sR[t - 32]  = Rm[h * 9 + (t - 32)]; }
    else if (t < 44) { st3[t - 41] = tv[h * 3 + (t - 41)]; }
    else if (t < 47) { ksc[t - 44] = scale[h * 3 + (t - 44)];
                       ksh[t - 44] = shift[h * 3 + (t - 44)]; }
    __syncthreads();

    float* const og = out + ((size_t)g << 20);

    #pragma unroll
    for (int pp = 0; pp < 2; ++pp) {
        const int n = (chunk << 9) + (pp << 8) + t;

        const float k0 = fmaf(keys[(size_t)(g * 3 + 0) * Nn + n], ksc[0], ksh[0]);
        const float k1 = fmaf(keys[(size_t)(g * 3 + 1) * Nn + n], ksc[1], ksh[1]);
        const float k2 = fmaf(keys[(size_t)(g * 3 + 2) * Nn + n], ksc[2], ksh[2]);
        const float p0 = orig[(size_t)(b * 3 + 0) * Nn + n] + k0;
        const float p1 = orig[(size_t)(b * 3 + 1) * Nn + n] + k1;
        const float p2 = orig[(size_t)(b * 3 + 2) * Nn + n] + k2;

        int   idx[3];
        float loc[3];
        #pragma unroll
        for (int d = 0; d < 3; ++d) {
            const float tk = fmaf(sR[d*3+0], p0, fmaf(sR[d*3+1], p1, fmaf(sR[d*3+2], p2, st3[d])));
            const float la = tanhf(tk);
            const float po = (la + 1.f) * 15.5f;
            float fi = floorf(po);
            fi = fminf(fmaxf(fi, 0.f), 30.f);
            idx[d] = (int)fi;
            loc[d] = po - fi;
        }
        const int cell = (idx[0] * Gg + idx[1]) * Gg + idx[2];

        float v[32];
        const float4* vp = reinterpret_cast<const float4*>(vals + ((size_t)g * Nn + n) * Ff);
        #pragma unroll
        for (int q = 0; q < 8; ++q) {
            const float4 xq = vp[q];
            v[4*q+0] = fmaf(xq.x, sc[4*q+0], sh[4*q+0]);
            v[4*q+1] = fmaf(xq.y, sc[4*q+1], sh[4*q+1]);
            v[4*q+2] = fmaf(xq.z, sc[4*q+2], sh[4*q+2]);
            v[4*q+3] = fmaf(xq.w, sc[4*q+3], sh[4*q+3]);
        }

        const float wx1 = loc[0], wx0 = 1.f - loc[0];
        const float wy1 = loc[1], wy0 = 1.f - loc[1];
        const float wz1 = loc[2], wz0 = 1.f - loc[2];
        const float cw[8] = { wx0*wy0*wz0, wx0*wy0*wz1, wx0*wy1*wz0, wx0*wy1*wz1,
                              wx1*wy0*wz0, wx1*wy0*wz1, wx1*wy1*wz0, wx1*wy1*wz1 };
        const int  co[8] = { 0, 1, 32, 33, 1024, 1025, 1056, 1057 };

        #pragma unroll
        for (int ff = 0; ff < 32; ++ff) {
            float* const pf = og + (size_t)ff * G3v + cell;
            const float vf = v[ff];
            #pragma unroll
            for (int c8 = 0; c8 < 8; ++c8) {
                atomicAdd(pf + co[c8], cw[c8] * vf);
            }
        }
    }
}

extern "C" void kernel_launch(void* const* d_in, const int* in_sizes, int n_in,
                              void* d_out, int out_size, void* d_ws, size_t ws_size,
                              hipStream_t stream)
{
    const float* X    = (const float*)d_in[0];
    const float* orig = (const float*)d_in[1];
    const float* W    = (const float*)d_in[2];
    const float* kg   = (const float*)d_in[3];
    const float* kb   = (const float*)d_in[4];
    const float* vg   = (const float*)d_in[5];
    const float* vb   = (const float*)d_in[6];
    const float* Rm   = (const float*)d_in[7];
    const float* tv   = (const float*)d_in[8];
    float* out = (float*)d_out;
    float* ws  = (float*)d_ws;

    // float-offset workspace layout
    float* vals  = ws;                          // 16,777,216
    float* keys  = ws + 16777216;               //  1,572,864
    float* gsum  = ws + 18350080;               // 140
    float* gsq   = gsum + 140;
    float* scale = gsum + 280;
    float* shift = scale + 140;
    int*   cnt    = (int*)(ws + 18350848);      // 953,312
    int*   basep  = (int*)(ws + 19304160);      // 953,312
    int*   cursor = (int*)(ws + 20257472);      // 953,312
    int*   bsum   = (int*)(ws + 21210784);      // 1,024
    int*   bscan  = (int*)(ws + 21211808);      // 1,024
    float4* rec    = (float4*)(ws + 21212832);  // 524,288 float4
    float4* binned = (float4*)(ws + 23309984);  // 524,288 float4
    unsigned short* Wbf = (unsigned short*)(ws + 25407136); // 40,960 bf16
    const size_t need_bytes = (size_t)25427616 * sizeof(float);   // ~101.7 MiB

    hipMemsetAsync(gsum, 0, 280 * sizeof(float), stream);

    prep_w_kernel<<<160, 256, 0, stream>>>(W, Wbf);
    gemm_stats_kernel<<<1024, 256, 0, stream>>>(X, Wbf, vals, keys, gsum, gsq);
    finalize_kernel<<<1, 256, 0, stream>>>(gsum, gsq, kg, kb, vg, vb, scale, shift);

    if (ws_size >= need_bytes) {
        hipMemsetAsync(cnt, 0, (size_t)NB2 * sizeof(int), stream);
        points_kernel<<<2048, 256, 0, stream>>>(keys, orig, Rm, tv, scale, shift, rec, cnt);
        scan1_kernel<<<NCH, 256, 0, stream>>>(cnt, bsum);
        scan2_kernel<<<1, 1024, 0, stream>>>(bsum, bscan);
        scan3_kernel<<<NCH, 256, 0, stream>>>(cnt, bscan, basep, cursor);
        fill_kernel<<<2048, 256, 0, stream>>>(rec, cursor, binned);
        gather_kernel<<<2048, 1024, 0, stream>>>(vals, binned, basep, cnt, scale, shift, out);
    } else {
        hipMemsetAsync(out, 0, (size_t)out_size * sizeof(float), stream);
        scatter_kernel<<<1024, 256, 0, stream>>>(vals, keys, orig, Rm, tv, scale, shift, out);
    }
}

// Round 16
// 282.597 us; speedup vs baseline: 1.1263x; 1.0139x over previous
//
#include <hip/hip_runtime.h>
#include <hip/hip_bf16.h>
#include <cstddef>

#define Bz 8
#define Nn 16384
#define MD 256
#define Ff 32
#define Hh 4
#define Gg 32
#define G3v 32768
#define CKV 140
#define NG 32            // B*H groups
#define NBX 31           // x0 in [0,30]
#define NBY 31           // y0 in [0,30]
#define NBZ 31           // z0 in [0,30]
#define NB2 953312       // NG*NBX*NBY*NBZ
#define NCH 931          // ceil(NB2/1024)

using bf16x8 = __attribute__((ext_vector_type(8))) short;
using f32x16 = __attribute__((ext_vector_type(16))) float;

__device__ __forceinline__ unsigned bf16rne(float f) {
    unsigned u = __float_as_uint(f);
    return (u + 0x7fffu + ((u >> 16) & 1u)) >> 16;
}
__device__ __forceinline__ unsigned cvt2(float lo, float hi) {
    __hip_bfloat162 hb = __float22bfloat162_rn(make_float2(lo, hi));
    union { __hip_bfloat162 b; unsigned u; } c;
    c.b = hb;
    return c.u;
}

// ---------------- Pass 0: W -> bf16, MFMA-fragment order [k>>3][m][k&7], pad m to 160 ----
__global__ __launch_bounds__(256) void prep_w_kernel(const float* __restrict__ W,
                                                     unsigned short* __restrict__ Wbf)
{
    const int idx = blockIdx.x * 256 + threadIdx.x;   // 0..40959
    const int e    = idx & 7;
    const int rest = idx >> 3;
    const int m    = rest % 160;
    const int kg   = rest / 160;
    const int k    = (kg << 3) + e;
    Wbf[idx] = (m < CKV) ? (unsigned short)bf16rne(W[m * MD + k]) : (unsigned short)0;
}

// ---------------- Pass 1: kv = W·X via bf16 MFMA; W fragments from L2; no stats ----------------
__global__ __launch_bounds__(256, 3) void gemm_stats_kernel(
    const float* __restrict__ X, const unsigned short* __restrict__ Wbf,
    float* __restrict__ vals, float* __restrict__ keys)
{
    __shared__ float smem[4608];     // 18.4 KB: staging XlU (4096 dw) / transpose [128][36]
    unsigned* XlU = reinterpret_cast<unsigned*>(smem);

    const int bid = blockIdx.x;
    const int b   = bid >> 7;
    const int n0  = (bid & 127) << 7;
    const int t   = threadIdx.x;
    const int w   = t >> 6;
    const int ln  = t & 31;
    const int hi  = (t >> 5) & 1;

    f32x16 acc[5];
    #pragma unroll
    for (int mt = 0; mt < 5; ++mt)
        #pragma unroll
        for (int j = 0; j < 16; ++j) acc[mt][j] = 0.f;

    for (int ks = 0; ks < 4; ++ks) {
        const int k0 = ks << 6;
        if (ks > 0) __syncthreads();

        // stage X tile [64 k][128 n] -> bf16 transposed [k>>3][n][k&7]
        #pragma unroll
        for (int it = 0; it < 4; ++it) {
            const int a  = t + (it << 8);
            const int kp = a >> 5;            // k-pair 0..31 (k = 2kp, 2kp+1)
            const int n4 = (a & 31) << 2;
            const float4 r0 = *reinterpret_cast<const float4*>(
                X + (size_t)(b * MD + k0 + 2 * kp) * Nn + n0 + n4);
            const float4 r1 = *reinterpret_cast<const float4*>(
                X + (size_t)(b * MD + k0 + 2 * kp + 1) * Nn + n0 + n4);
            const int base = ((kp >> 2) << 9) + (n4 << 2) + (kp & 3);
            XlU[base]      = cvt2(r0.x, r1.x);
            XlU[base + 4]  = cvt2(r0.y, r1.y);
            XlU[base + 8]  = cvt2(r0.z, r1.z);
            XlU[base + 12] = cvt2(r0.w, r1.w);
        }
        __syncthreads();

        const short* xs = reinterpret_cast<const short*>(XlU);
        const short* wsg = reinterpret_cast<const short*>(Wbf) + (k0 << 7) * 5; // ks*5120 dwords = ks*10240 shorts... (k0/8)*160*8 = k0*160 = ks*10240
        #pragma unroll
        for (int kk = 0; kk < 4; ++kk) {
            const int grp = (kk << 1) + hi;
            const bf16x8 bf = *reinterpret_cast<const bf16x8*>(
                xs + (((grp << 7) + (w << 5) + ln) << 3));
            #pragma unroll
            for (int mt = 0; mt < 5; ++mt) {
                const bf16x8 af = *reinterpret_cast<const bf16x8*>(
                    reinterpret_cast<const short*>(Wbf) +
                    ((((k0 >> 3) + grp) * 160 + (mt << 5) + ln) << 3));
                acc[mt] = __builtin_amdgcn_mfma_f32_32x32x16_bf16(af, bf, acc[mt], 0, 0, 0);
            }
        }
    }

    // ---- keys direct store (c<12): lanes contiguous in n -> coalesced ----
    const int n = n0 + (w << 5) + ln;
    #pragma unroll
    for (int reg = 0; reg < 8; ++reg) {
        const int ml = (reg & 3) + ((reg >> 2) << 3) + (hi << 2);
        if (ml < 12) {
            const int hh = ml / 3, kk2 = ml - (ml / 3) * 3;
            keys[(size_t)((b * Hh + hh) * 3 + kk2) * Nn + n] = acc[0][reg];
        }
    }

    // ---- vals: per-mt LDS transpose -> coalesced float4 stores along f ----
    const int nl = (w << 5) + ln;     // block-local column 0..127
    #pragma unroll
    for (int mt = 0; mt < 5; ++mt) {
        __syncthreads();
        #pragma unroll
        for (int reg = 0; reg < 16; ++reg) {
            const int ml = (reg & 3) + ((reg >> 2) << 3) + (hi << 2);
            smem[nl * 36 + ml] = acc[mt][reg];
        }
        __syncthreads();
        #pragma unroll
        for (int i = 0; i < 4; ++i) {
            const int id = t + (i << 8);
            const int nn = id >> 3;           // 0..127
            const int q  = id & 7;            // channel quad within mt tile
            const int c  = (mt << 5) + (q << 2);
            if (c < 12 || c >= CKV) continue;
            const int cv = c - 12;
            const float4 v4 = *reinterpret_cast<const float4*>(&smem[nn * 36 + (q << 2)]);
            *reinterpret_cast<float4*>(
                &vals[((size_t)(b * Hh + (cv >> 5)) * Nn + n0 + nn) * Ff + (cv & 31)]) = v4;
        }
    }
}

// ---------------- Pass 1b: BN statistics from keys (12 channels) ----------------
__global__ __launch_bounds__(256) void stats_keys_kernel(
    const float* __restrict__ keys, float* __restrict__ gsum, float* __restrict__ gsq)
{
    const int g = blockIdx.x;        // b*4+h, 32 blocks
    const int t = threadIdx.x;
    __shared__ float rs[6];
    if (t < 6) rs[t] = 0.f;
    __syncthreads();
    #pragma unroll
    for (int kk = 0; kk < 3; ++kk) {
        const float* p = keys + (size_t)(g * 3 + kk) * Nn;
        float s = 0.f, q = 0.f;
        for (int i = t * 4; i < Nn; i += 1024) {
            const float4 v = *reinterpret_cast<const float4*>(p + i);
            s += v.x + v.y + v.z + v.w;
            q += v.x * v.x + v.y * v.y + v.z * v.z + v.w * v.w;
        }
        #pragma unroll
        for (int off = 1; off < 64; off <<= 1) { s += __shfl_xor(s, off); q += __shfl_xor(q, off); }
        if ((t & 63) == 0) { atomicAdd(&rs[kk], s); atomicAdd(&rs[3 + kk], q); }
    }
    __syncthreads();
    if (t < 3) {
        atomicAdd(&gsum[(g & 3) * 3 + t], rs[t]);
        atomicAdd(&gsq[(g & 3) * 3 + t],  rs[3 + t]);
    }
}

// ---------------- Pass 1c: BN statistics from vals (128 channels) ----------------
__global__ __launch_bounds__(256) void stats_vals_kernel(
    const float* __restrict__ vals, float* __restrict__ gsum, float* __restrict__ gsq)
{
    const int bid   = blockIdx.x;      // 1024 blocks
    const int g     = bid >> 5;
    const int chunk = bid & 31;        // 512 n each
    const int h     = g & 3;
    const int t     = threadIdx.x;
    const int fq    = t & 7;
    const int nl    = t >> 3;          // 0..31
    __shared__ float red[64];
    if (t < 64) red[t] = 0.f;
    __syncthreads();

    float s0 = 0, s1 = 0, s2 = 0, s3 = 0, q0 = 0, q1 = 0, q2 = 0, q3 = 0;
    const float* base = vals + ((size_t)g * Nn + chunk * 512) * Ff + fq * 4;
    #pragma unroll
    for (int i = 0; i < 16; ++i) {
        const float4 v = *reinterpret_cast<const float4*>(base + (size_t)(nl + i * 32) * Ff);
        s0 += v.x; s1 += v.y; s2 += v.z; s3 += v.w;
        q0 += v.x * v.x; q1 += v.y * v.y; q2 += v.z * v.z; q3 += v.w * v.w;
    }
    #pragma unroll
    for (int off = 8; off < 64; off <<= 1) {
        s0 += __shfl_xor(s0, off); s1 += __shfl_xor(s1, off);
        s2 += __shfl_xor(s2, off); s3 += __shfl_xor(s3, off);
        q0 += __shfl_xor(q0, off); q1 += __shfl_xor(q1, off);
        q2 += __shfl_xor(q2, off); q3 += __shfl_xor(q3, off);
    }
    if ((t & 56) == 0) {               // lane < 8 within each wave
        atomicAdd(&red[fq * 4 + 0], s0); atomicAdd(&red[fq * 4 + 1], s1);
        atomicAdd(&red[fq * 4 + 2], s2); atomicAdd(&red[fq * 4 + 3], s3);
        atomicAdd(&red[32 + fq * 4 + 0], q0); atomicAdd(&red[32 + fq * 4 + 1], q1);
        atomicAdd(&red[32 + fq * 4 + 2], q2); atomicAdd(&red[32 + fq * 4 + 3], q3);
    }
    __syncthreads();
    if (t < 32) {
        atomicAdd(&gsum[12 + h * 32 + t], red[t]);
        atomicAdd(&gsq[12 + h * 32 + t],  red[32 + t]);
    }
}

// ---------------- Pass 2: finalize BN affine params ----------------
__global__ void finalize_kernel(const float* __restrict__ gsum, const float* __restrict__ gsq,
                                const float* __restrict__ kg, const float* __restrict__ kb,
                                const float* __restrict__ vg, const float* __restrict__ vb,
                                float* __restrict__ scale, float* __restrict__ shift)
{
    const int c = threadIdx.x;
    if (c < CKV) {
        const float inv = 1.f / (float)(Bz * Nn);
        const float m = gsum[c] * inv;
        const float v = fmaf(-m, m, gsq[c] * inv);
        float ga, be;
        if (c < 12) { ga = kg[c]; be = kb[c]; }
        else        { ga = vg[c - 12]; be = vb[c - 12]; }
        const float sc = ga * rsqrtf(v + 1e-5f);
        scale[c] = sc;
        shift[c] = fmaf(-m, sc, be);
    }
}

// ---------------- Pass 3a: per-point transform -> record + (g,x0,y0,z0) histogram ----------------
__global__ __launch_bounds__(256) void points_kernel(
    const float* __restrict__ keys, const float* __restrict__ orig,
    const float* __restrict__ Rm, const float* __restrict__ tv,
    const float* __restrict__ scale, const float* __restrict__ shift,
    float4* __restrict__ rec, int* __restrict__ cnt)
{
    const int bid = blockIdx.x;
    const int g   = bid >> 6;
    const int b   = g >> 2;
    const int h   = g & 3;
    const int t   = threadIdx.x;
    const int n   = ((bid & 63) << 8) + t;

    __shared__ float sR[9], st3[3], ksc[3], ksh[3];
    if (t < 9)       sR[t] = Rm[h * 9 + t];
    else if (t < 12) st3[t - 9] = tv[h * 3 + (t - 9)];
    else if (t < 15) { ksc[t - 12] = scale[h * 3 + (t - 12)];
                       ksh[t - 12] = shift[h * 3 + (t - 12)]; }
    __syncthreads();

    const float k0 = fmaf(keys[(size_t)(g * 3 + 0) * Nn + n], ksc[0], ksh[0]);
    const float k1 = fmaf(keys[(size_t)(g * 3 + 1) * Nn + n], ksc[1], ksh[1]);
    const float k2 = fmaf(keys[(size_t)(g * 3 + 2) * Nn + n], ksc[2], ksh[2]);
    const float p0 = orig[(size_t)(b * 3 + 0) * Nn + n] + k0;
    const float p1 = orig[(size_t)(b * 3 + 1) * Nn + n] + k1;
    const float p2 = orig[(size_t)(b * 3 + 2) * Nn + n] + k2;

    int   idx[3];
    float loc[3];
    #pragma unroll
    for (int d = 0; d < 3; ++d) {
        const float tk = fmaf(sR[d*3+0], p0, fmaf(sR[d*3+1], p1, fmaf(sR[d*3+2], p2, st3[d])));
        const float la = tanhf(tk);
        const float po = (la + 1.f) * 15.5f;
        float fi = floorf(po);
        fi = fminf(fmaxf(fi, 0.f), 30.f);
        idx[d] = (int)fi;
        loc[d] = po - fi;
    }

    const unsigned meta = (unsigned)n | ((unsigned)idx[2] << 14) |
                          ((unsigned)idx[1] << 19) | ((unsigned)idx[0] << 24);
    float4 r;
    r.x = __uint_as_float(meta);
    r.y = loc[0]; r.z = loc[1]; r.w = loc[2];
    rec[(size_t)g * Nn + n] = r;
    const int key = ((g * NBX + idx[0]) * NBY + idx[1]) * NBZ + idx[2];
    atomicAdd(&cnt[key], 1);
}

// ---------------- Pass 3b: hierarchical exclusive scan over 953312 bins ----------------
__global__ __launch_bounds__(256) void scan1_kernel(const int* __restrict__ cnt,
                                                    int* __restrict__ bsum)
{
    __shared__ int s[256];
    const int t = threadIdx.x;
    const int i = blockIdx.x * 1024 + t * 4;
    int v = 0;
    #pragma unroll
    for (int j = 0; j < 4; ++j) { const int idx = i + j; if (idx < NB2) v += cnt[idx]; }
    s[t] = v;
    __syncthreads();
    for (int off = 128; off > 0; off >>= 1) {
        if (t < off) s[t] += s[t + off];
        __syncthreads();
    }
    if (t == 0) bsum[blockIdx.x] = s[0];
}

__global__ __launch_bounds__(1024) void scan2_kernel(const int* __restrict__ bsum,
                                                     int* __restrict__ bscan)
{
    __shared__ int s[1024];
    const int t = threadIdx.x;
    const int v = (t < NCH) ? bsum[t] : 0;
    s[t] = v;
    __syncthreads();
    for (int off = 1; off < 1024; off <<= 1) {
        const int x = (t >= off) ? s[t - off] : 0;
        __syncthreads();
        s[t] += x;
        __syncthreads();
    }
    if (t < NCH) bscan[t] = s[t] - v;   // exclusive
}

__global__ __launch_bounds__(256) void scan3_kernel(const int* __restrict__ cnt,
                                                    const int* __restrict__ bscan,
                                                    int* __restrict__ basep,
                                                    int* __restrict__ cursor)
{
    __shared__ int s[256];
    const int t = threadIdx.x;
    const int i = blockIdx.x * 1024 + t * 4;
    int c[4], l[4];
    int sum = 0;
    #pragma unroll
    for (int j = 0; j < 4; ++j) {
        const int idx = i + j;
        c[j] = (idx < NB2) ? cnt[idx] : 0;
        l[j] = sum; sum += c[j];
    }
    s[t] = sum;
    __syncthreads();
    for (int off = 1; off < 256; off <<= 1) {
        const int x = (t >= off) ? s[t - off] : 0;
        __syncthreads();
        s[t] += x;
        __syncthreads();
    }
    const int off0 = bscan[blockIdx.x] + s[t] - sum;
    #pragma unroll
    for (int j = 0; j < 4; ++j) {
        const int idx = i + j;
        if (idx < NB2) { basep[idx] = off0 + l[j]; cursor[idx] = off0 + l[j]; }
    }
}

// ---------------- Pass 3c: counting-sort records into (g,x0,y0,z0) bins ----------------
__global__ __launch_bounds__(256) void fill_kernel(
    const float4* __restrict__ rec, int* __restrict__ cursor,
    float4* __restrict__ binned)
{
    const int bid = blockIdx.x;
    const int g   = bid >> 6;
    const int t   = threadIdx.x;
    const int n   = ((bid & 63) << 8) + t;
    const float4 r = rec[(size_t)g * Nn + n];
    const unsigned meta = __float_as_uint(r.x);
    const int x0 = (meta >> 24) & 31;
    const int y0 = (meta >> 19) & 31;
    const int z0 = (meta >> 14) & 31;
    const int key = ((g * NBX + x0) * NBY + y0) * NBZ + z0;
    const int pos = atomicAdd(&cursor[key], 1);
    binned[pos] = r;
}

// ---------------- Pass 3d: gather via MFMA outer products ----------------
#define MKAB(qe, ridx, ae, ve)                                               \
{                                                                            \
    const unsigned mq = __float_as_uint((qe).x);                             \
    const int z0 = (int)((mq >> 14) & 31u);                                  \
    const float wx  = dx ? (1.f - (qe).y) : (qe).y;                          \
    const float wy  = dy ? (1.f - (qe).z) : (qe).z;                          \
    const float wxy = ((ridx) < e) ? wx * wy : 0.f;                          \
    const float lz  = (qe).w;                                                \
    ae = (ln == z0) ? (1.f - lz) * wxy                                       \
                    : ((ln == z0 + 1) ? lz * wxy : 0.f);                     \
    ve = fmaf(vg[(((size_t)(mq & 16383u)) << 5) + ln], scf, shf);            \
}

__global__ __launch_bounds__(1024) void gather_kernel(
    const float* __restrict__ vals, const float4* __restrict__ binned,
    const int* __restrict__ basep, const int* __restrict__ cnt,
    const float* __restrict__ scale, const float* __restrict__ shift,
    float* __restrict__ out)
{
    __shared__ float tile[16384];
    __shared__ float sscale[32], sshift[32];

    const int bid = blockIdx.x;
    const int g   = bid & 31;
    const int x   = (bid >> 5) & 31;
    const int yh  = bid >> 10;
    const int h   = g & 3;
    const int t   = threadIdx.x;

    if (t < 32) { sscale[t] = scale[12 + h * 32 + t]; sshift[t] = shift[12 + h * 32 + t]; }
    __syncthreads();

    const int ln = t & 31;            // A row (z) / B col (f)
    const int hi = (t >> 5) & 1;      // k-octet select
    const int w  = t >> 6;            // wave id 0..15
    const int y  = (yh << 4) + w;     // owned output row
    const float scf = sscale[ln], shf = sshift[ln];
    const float* vg = vals + ((size_t)g << 19);   // g * Nn * Ff

    f32x16 acc;
    #pragma unroll
    for (int j = 0; j < 16; ++j) acc[j] = 0.f;

    #pragma unroll
    for (int dy = 0; dy < 2; ++dy) {
        const int y0 = y - 1 + dy;                // dy=0: wy=q.z ; dy=1: wy=1-q.z
        if ((unsigned)y0 > 30u) continue;
        #pragma unroll
        for (int dx = 0; dx < 2; ++dx) {
            const int x0 = x - 1 + dx;
            if ((unsigned)x0 > 30u) continue;
            const int kb = ((g * NBX + x0) * NBY + y0) * NBZ;
            int r       = basep[kb];
            const int e = basep[kb + 30] + cnt[kb + 30];

            for (; r < e; r += 16) {
                const int base = r + (hi << 3);
                const int eM1  = e - 1;
                const int r0 = min(base,     eM1);
                const int r1 = min(base + 1, eM1);
                const int r2 = min(base + 2, eM1);
                const int r3 = min(base + 3, eM1);
                const int r4 = min(base + 4, eM1);
                const int r5 = min(base + 5, eM1);
                const int r6 = min(base + 6, eM1);
                const int r7 = min(base + 7, eM1);
                const float4 q0 = binned[r0];
                const float4 q1 = binned[r1];
                const float4 q2 = binned[r2];
                const float4 q3 = binned[r3];
                const float4 q4 = binned[r4];
                const float4 q5 = binned[r5];
                const float4 q6 = binned[r6];
                const float4 q7 = binned[r7];
                float a0, a1, a2, a3, a4, a5, a6, a7;
                float v0, v1, v2, v3, v4, v5, v6, v7;
                MKAB(q0, base,     a0, v0);
                MKAB(q1, base + 1, a1, v1);
                MKAB(q2, base + 2, a2, v2);
                MKAB(q3, base + 3, a3, v3);
                MKAB(q4, base + 4, a4, v4);
                MKAB(q5, base + 5, a5, v5);
                MKAB(q6, base + 6, a6, v6);
                MKAB(q7, base + 7, a7, v7);
                union { bf16x8 v; unsigned u[4]; } af, bf;
                af.u[0] = cvt2(a0, a1); af.u[1] = cvt2(a2, a3);
                af.u[2] = cvt2(a4, a5); af.u[3] = cvt2(a6, a7);
                bf.u[0] = cvt2(v0, v1); bf.u[1] = cvt2(v2, v3);
                bf.u[2] = cvt2(v4, v5); bf.u[3] = cvt2(v6, v7);
                acc = __builtin_amdgcn_mfma_f32_32x32x16_bf16(af.v, bf.v, acc, 0, 0, 0);
            }
        }
    }

    // write acc -> wave tile: C[row=z][col=f], stored swizzled [z][f^z]
    float* const tg = &tile[w << 10];
    #pragma unroll
    for (int reg = 0; reg < 16; ++reg) {
        const int zr = (reg & 3) + ((reg >> 2) << 3) + (hi << 2);
        tg[(zr << 5) + ((ln ^ zr) & 31)] = acc[reg];
    }
    __syncthreads();

    // write out[(g*32+fp)*G3 + x*1024 + yh*512 + row*32 + z]
    float* og = out + ((size_t)g << 20) + (x << 10) + (yh << 9);
    #pragma unroll
    for (int i = 0; i < 16; ++i) {
        const int lin = t + (i << 10);
        const int fp  = lin >> 9;          // 0..31
        const int s   = lin & 511;         // row*32 + z
        const int z   = s & 31;
        og[((size_t)fp << 15) + s] = tile[((s >> 5) << 10) + (z << 5) + ((fp ^ z) & 31)];
    }
}

// ---------------- Fallback: direct-layout global-atomic scatter ----------------
__global__ __launch_bounds__(256) void scatter_kernel(
    const float* __restrict__ vals, const float* __restrict__ keys,
    const float* __restrict__ orig, const float* __restrict__ Rm,
    const float* __restrict__ tv, const float* __restrict__ scale,
    const float* __restrict__ shift, float* __restrict__ out)
{
    const int bid   = blockIdx.x;
    const int g     = bid >> 5;
    const int chunk = bid & 31;
    const int b     = g >> 2;
    const int h     = g & 3;

    __shared__ float sc[32], sh[32], sR[9], st3[3], ksc[3], ksh[3];
    const int t = threadIdx.x;
    if (t < 32)      { sc[t] = scale[12 + h * 32 + t]; sh[t] = shift[12 + h * 32 + t]; }
    else if (t < 41) { sR[t - 32]  = Rm[h * 9 + (t - 32)]; }
    else if (t < 44) { st3[t - 41] = tv[h * 3 + (t - 41)]; }
    else if (t < 47) { ksc[t - 44] = scale[h * 3 + (t - 44)];
                       ksh[t - 44] = shift[h * 3 + (t - 44)]; }
    __syncthreads();

    float* const og = out + ((size_t)g << 20);

    #pragma unroll
    for (int pp = 0; pp < 2; ++pp) {
        const int n = (chunk << 9) + (pp << 8) + t;

        const float k0 = fmaf(keys[(size_t)(g * 3 + 0) * Nn + n], ksc[0], ksh[0]);
        const float k1 = fmaf(keys[(size_t)(g * 3 + 1) * Nn + n], ksc[1], ksh[1]);
        const float k2 = fmaf(keys[(size_t)(g * 3 + 2) * Nn + n], ksc[2], ksh[2]);
        const float p0 = orig[(size_t)(b * 3 + 0) * Nn + n] + k0;
        const float p1 = orig[(size_t)(b * 3 + 1) * Nn + n] + k1;
        const float p2 = orig[(size_t)(b * 3 + 2) * Nn + n] + k2;

        int   idx[3];
        float loc[3];
        #pragma unroll
        for (int d = 0; d < 3; ++d) {
            const float tk = fmaf(sR[d*3+0], p0, fmaf(sR[d*3+1], p1, fmaf(sR[d*3+2], p2, st3[d])));
            const float la = tanhf(tk);
            const float po = (la + 1.f) * 15.5f;
            float fi = floorf(po);
            fi = fminf(fmaxf(fi, 0.f), 30.f);
            idx[d] = (int)fi;
            loc[d] = po - fi;
        }
        const int cell = (idx[0] * Gg + idx[1]) * Gg + idx[2];

        float v[32];
        const float4* vp = reinterpret_cast<const float4*>(vals + ((size_t)g * Nn + n) * Ff);
        #pragma unroll
        for (int q = 0; q < 8; ++q) {
            const float4 xq = vp[q];
            v[4*q+0] = fmaf(xq.x, sc[4*q+0], sh[4*q+0]);
            v[4*q+1] = fmaf(xq.y, sc[4*q+1], sh[4*q+1]);
            v[4*q+2] = fmaf(xq.z, sc[4*q+2], sh[4*q+2]);
            v[4*q+3] = fmaf(xq.w, sc[4*q+3], sh[4*q+3]);
        }

        const float wx1 = loc[0], wx0 = 1.f - loc[0];
        const float wy1 = loc[1], wy0 = 1.f - loc[1];
        const float wz1 = loc[2], wz0 = 1.f - loc[2];
        const float cw[8] = { wx0*wy0*wz0, wx0*wy0*wz1, wx0*wy1*wz0, wx0*wy1*wz1,
                              wx1*wy0*wz0, wx1*wy0*wz1, wx1*wy1*wz0, wx1*wy1*wz1 };
        const int  co[8] = { 0, 1, 32, 33, 1024, 1025, 1056, 1057 };

        #pragma unroll
        for (int ff = 0; ff < 32; ++ff) {
            float* const pf = og + (size_t)ff * G3v + cell;
            const float vf = v[ff];
            #pragma unroll
            for (int c8 = 0; c8 < 8; ++c8) {
                atomicAdd(pf + co[c8], cw[c8] * vf);
            }
        }
    }
}

extern "C" void kernel_launch(void* const* d_in, const int* in_sizes, int n_in,
                              void* d_out, int out_size, void* d_ws, size_t ws_size,
                              hipStream_t stream)
{
    const float* X    = (const float*)d_in[0];
    const float* orig = (const float*)d_in[1];
    const float* W    = (const float*)d_in[2];
    const float* kg   = (const float*)d_in[3];
    const float* kb   = (const float*)d_in[4];
    const float* vg   = (const float*)d_in[5];
    const float* vb   = (const float*)d_in[6];
    const float* Rm   = (const float*)d_in[7];
    const float* tv   = (const float*)d_in[8];
    float* out = (float*)d_out;
    float* ws  = (float*)d_ws;

    // float-offset workspace layout
    float* vals  = ws;                          // 16,777,216
    float* keys  = ws + 16777216;               //  1,572,864
    float* gsum  = ws + 18350080;               // 140
    float* gsq   = gsum + 140;
    float* scale = gsum + 280;
    float* shift = scale + 140;
    int*   cnt    = (int*)(ws + 18350848);      // 953,312
    int*   basep  = (int*)(ws + 19304160);      // 953,312
    int*   cursor = (int*)(ws + 20257472);      // 953,312
    int*   bsum   = (int*)(ws + 21210784);      // 1,024
    int*   bscan  = (int*)(ws + 21211808);      // 1,024
    float4* rec    = (float4*)(ws + 21212832);  // 524,288 float4
    float4* binned = (float4*)(ws + 23309984);  // 524,288 float4
    unsigned short* Wbf = (unsigned short*)(ws + 25407136); // 40,960 bf16
    const size_t need_bytes = (size_t)25427616 * sizeof(float);   // ~101.7 MiB

    hipMemsetAsync(gsum, 0, 280 * sizeof(float), stream);

    prep_w_kernel<<<160, 256, 0, stream>>>(W, Wbf);
    gemm_stats_kernel<<<1024, 256, 0, stream>>>(X, Wbf, vals, keys);
    stats_keys_kernel<<<32, 256, 0, stream>>>(keys, gsum, gsq);
    stats_vals_kernel<<<1024, 256, 0, stream>>>(vals, gsum, gsq);
    finalize_kernel<<<1, 256, 0, stream>>>(gsum, gsq, kg, kb, vg, vb, scale, shift);

    if (ws_size >= need_bytes) {
        hipMemsetAsync(cnt, 0, (size_t)NB2 * sizeof(int), stream);
        points_kernel<<<2048, 256, 0, stream>>>(keys, orig, Rm, tv, scale, shift, rec, cnt);
        scan1_kernel<<<NCH, 256, 0, stream>>>(cnt, bsum);
        scan2_kernel<<<1, 1024, 0, stream>>>(bsum, bscan);
        scan3_kernel<<<NCH, 256, 0, stream>>>(cnt, bscan, basep, cursor);
        fill_kernel<<<2048, 256, 0, stream>>>(rec, cursor, binned);
        gather_kernel<<<2048, 1024, 0, stream>>>(vals, binned, basep, cnt, scale, shift, out);
    } else {
        hipMemsetAsync(out, 0, (size_t)out_size * sizeof(float), stream);
        scatter_kernel<<<1024, 256, 0, stream>>>(vals, keys, orig, Rm, tv, scale, shift, out);
    }
}

// Round 17
// 259.812 us; speedup vs baseline: 1.2251x; 1.0877x over previous
//
#include <hip/hip_runtime.h>
#include <hip/hip_bf16.h>
#include <cstddef>

#define Bz 8
#define Nn 16384
#define MD 256
#define Ff 32
#define Hh 4
#define Gg 32
#define G3v 32768
#define CKV 140
#define NG 32            // B*H groups
#define NBX 31           // x0 in [0,30]
#define NBY 31           // y0 in [0,30]
#define NBZ 31           // z0 in [0,30]
#define NB2 953312       // NG*NBX*NBY*NBZ
#define NCH 931          // ceil(NB2/1024)

using bf16x8 = __attribute__((ext_vector_type(8))) short;
using f32x16 = __attribute__((ext_vector_type(16))) float;

__device__ __forceinline__ unsigned bf16rne(float f) {
    unsigned u = __float_as_uint(f);
    return (u + 0x7fffu + ((u >> 16) & 1u)) >> 16;
}
__device__ __forceinline__ unsigned cvt2(float lo, float hi) {
    __hip_bfloat162 hb = __float22bfloat162_rn(make_float2(lo, hi));
    union { __hip_bfloat162 b; unsigned u; } c;
    c.b = hb;
    return c.u;
}

// ---------------- Pass 0: W -> bf16, MFMA-fragment order [k>>3][m][k&7], pad m to 160 ----
__global__ __launch_bounds__(256) void prep_w_kernel(const float* __restrict__ W,
                                                     unsigned short* __restrict__ Wbf)
{
    const int idx = blockIdx.x * 256 + threadIdx.x;   // 0..40959
    const int e    = idx & 7;
    const int rest = idx >> 3;
    const int m    = rest % 160;
    const int kg   = rest / 160;
    const int k    = (kg << 3) + e;
    Wbf[idx] = (m < CKV) ? (unsigned short)bf16rne(W[m * MD + k]) : (unsigned short)0;
}

// ---------------- Pass 1: kv = W·X via bf16 MFMA; W fragments from L2; no stats ----------------
__global__ __launch_bounds__(256, 3) void gemm_stats_kernel(
    const float* __restrict__ X, const unsigned short* __restrict__ Wbf,
    float* __restrict__ vals, float* __restrict__ keys)
{
    __shared__ float smem[4608];     // 18.4 KB: staging XlU (4096 dw) / transpose [128][36]
    unsigned* XlU = reinterpret_cast<unsigned*>(smem);

    const int bid = blockIdx.x;
    const int b   = bid >> 7;
    const int n0  = (bid & 127) << 7;
    const int t   = threadIdx.x;
    const int w   = t >> 6;
    const int ln  = t & 31;
    const int hi  = (t >> 5) & 1;

    f32x16 acc[5];
    #pragma unroll
    for (int mt = 0; mt < 5; ++mt)
        #pragma unroll
        for (int j = 0; j < 16; ++j) acc[mt][j] = 0.f;

    for (int ks = 0; ks < 4; ++ks) {
        const int k0 = ks << 6;
        if (ks > 0) __syncthreads();

        #pragma unroll
        for (int it = 0; it < 4; ++it) {
            const int a  = t + (it << 8);
            const int kp = a >> 5;            // k-pair 0..31 (k = 2kp, 2kp+1)
            const int n4 = (a & 31) << 2;
            const float4 r0 = *reinterpret_cast<const float4*>(
                X + (size_t)(b * MD + k0 + 2 * kp) * Nn + n0 + n4);
            const float4 r1 = *reinterpret_cast<const float4*>(
                X + (size_t)(b * MD + k0 + 2 * kp + 1) * Nn + n0 + n4);
            const int base = ((kp >> 2) << 9) + (n4 << 2) + (kp & 3);
            XlU[base]      = cvt2(r0.x, r1.x);
            XlU[base + 4]  = cvt2(r0.y, r1.y);
            XlU[base + 8]  = cvt2(r0.z, r1.z);
            XlU[base + 12] = cvt2(r0.w, r1.w);
        }
        __syncthreads();

        const short* xs = reinterpret_cast<const short*>(XlU);
        #pragma unroll
        for (int kk = 0; kk < 4; ++kk) {
            const int grp = (kk << 1) + hi;
            const bf16x8 bf = *reinterpret_cast<const bf16x8*>(
                xs + (((grp << 7) + (w << 5) + ln) << 3));
            #pragma unroll
            for (int mt = 0; mt < 5; ++mt) {
                const bf16x8 af = *reinterpret_cast<const bf16x8*>(
                    reinterpret_cast<const short*>(Wbf) +
                    ((((k0 >> 3) + grp) * 160 + (mt << 5) + ln) << 3));
                acc[mt] = __builtin_amdgcn_mfma_f32_32x32x16_bf16(af, bf, acc[mt], 0, 0, 0);
            }
        }
    }

    // ---- keys direct store (c<12): lanes contiguous in n -> coalesced ----
    const int n = n0 + (w << 5) + ln;
    #pragma unroll
    for (int reg = 0; reg < 8; ++reg) {
        const int ml = (reg & 3) + ((reg >> 2) << 3) + (hi << 2);
        if (ml < 12) {
            const int hh = ml / 3, kk2 = ml - (ml / 3) * 3;
            keys[(size_t)((b * Hh + hh) * 3 + kk2) * Nn + n] = acc[0][reg];
        }
    }

    // ---- vals: per-mt LDS transpose -> coalesced float4 stores along f ----
    const int nl = (w << 5) + ln;     // block-local column 0..127
    #pragma unroll
    for (int mt = 0; mt < 5; ++mt) {
        __syncthreads();
        #pragma unroll
        for (int reg = 0; reg < 16; ++reg) {
            const int ml = (reg & 3) + ((reg >> 2) << 3) + (hi << 2);
            smem[nl * 36 + ml] = acc[mt][reg];
        }
        __syncthreads();
        #pragma unroll
        for (int i = 0; i < 4; ++i) {
            const int id = t + (i << 8);
            const int nn = id >> 3;           // 0..127
            const int q  = id & 7;            // channel quad within mt tile
            const int c  = (mt << 5) + (q << 2);
            if (c < 12 || c >= CKV) continue;
            const int cv = c - 12;
            const float4 v4 = *reinterpret_cast<const float4*>(&smem[nn * 36 + (q << 2)]);
            *reinterpret_cast<float4*>(
                &vals[((size_t)(b * Hh + (cv >> 5)) * Nn + n0 + nn) * Ff + (cv & 31)]) = v4;
        }
    }
}

// ---------------- Pass 1b: BN statistics from keys (12 channels) ----------------
__global__ __launch_bounds__(256) void stats_keys_kernel(
    const float* __restrict__ keys, float* __restrict__ gsum, float* __restrict__ gsq)
{
    const int g = blockIdx.x;        // b*4+h, 32 blocks
    const int t = threadIdx.x;
    __shared__ float rs[6];
    if (t < 6) rs[t] = 0.f;
    __syncthreads();
    #pragma unroll
    for (int kk = 0; kk < 3; ++kk) {
        const float* p = keys + (size_t)(g * 3 + kk) * Nn;
        float s = 0.f, q = 0.f;
        for (int i = t * 4; i < Nn; i += 1024) {
            const float4 v = *reinterpret_cast<const float4*>(p + i);
            s += v.x + v.y + v.z + v.w;
            q += v.x * v.x + v.y * v.y + v.z * v.z + v.w * v.w;
        }
        #pragma unroll
        for (int off = 1; off < 64; off <<= 1) { s += __shfl_xor(s, off); q += __shfl_xor(q, off); }
        if ((t & 63) == 0) { atomicAdd(&rs[kk], s); atomicAdd(&rs[3 + kk], q); }
    }
    __syncthreads();
    if (t < 3) {
        atomicAdd(&gsum[(g & 3) * 3 + t], rs[t]);
        atomicAdd(&gsq[(g & 3) * 3 + t],  rs[3 + t]);
    }
}

// ---------------- Pass 1c: BN statistics from vals (128 channels) ----------------
__global__ __launch_bounds__(256) void stats_vals_kernel(
    const float* __restrict__ vals, float* __restrict__ gsum, float* __restrict__ gsq)
{
    const int bid   = blockIdx.x;      // 1024 blocks
    const int g     = bid >> 5;
    const int chunk = bid & 31;        // 512 n each
    const int h     = g & 3;
    const int t     = threadIdx.x;
    const int fq    = t & 7;
    const int nl    = t >> 3;          // 0..31
    __shared__ float red[64];
    if (t < 64) red[t] = 0.f;
    __syncthreads();

    float s0 = 0, s1 = 0, s2 = 0, s3 = 0, q0 = 0, q1 = 0, q2 = 0, q3 = 0;
    const float* base = vals + ((size_t)g * Nn + chunk * 512) * Ff + fq * 4;
    #pragma unroll
    for (int i = 0; i < 16; ++i) {
        const float4 v = *reinterpret_cast<const float4*>(base + (size_t)(nl + i * 32) * Ff);
        s0 += v.x; s1 += v.y; s2 += v.z; s3 += v.w;
        q0 += v.x * v.x; q1 += v.y * v.y; q2 += v.z * v.z; q3 += v.w * v.w;
    }
    #pragma unroll
    for (int off = 8; off < 64; off <<= 1) {
        s0 += __shfl_xor(s0, off); s1 += __shfl_xor(s1, off);
        s2 += __shfl_xor(s2, off); s3 += __shfl_xor(s3, off);
        q0 += __shfl_xor(q0, off); q1 += __shfl_xor(q1, off);
        q2 += __shfl_xor(q2, off); q3 += __shfl_xor(q3, off);
    }
    if ((t & 56) == 0) {               // lane < 8 within each wave
        atomicAdd(&red[fq * 4 + 0], s0); atomicAdd(&red[fq * 4 + 1], s1);
        atomicAdd(&red[fq * 4 + 2], s2); atomicAdd(&red[fq * 4 + 3], s3);
        atomicAdd(&red[32 + fq * 4 + 0], q0); atomicAdd(&red[32 + fq * 4 + 1], q1);
        atomicAdd(&red[32 + fq * 4 + 2], q2); atomicAdd(&red[32 + fq * 4 + 3], q3);
    }
    __syncthreads();
    if (t < 32) {
        atomicAdd(&gsum[12 + h * 32 + t], red[t]);
        atomicAdd(&gsq[12 + h * 32 + t],  red[32 + t]);
    }
}

// ---------------- Pass 2: finalize BN affine params ----------------
__global__ void finalize_kernel(const float* __restrict__ gsum, const float* __restrict__ gsq,
                                const float* __restrict__ kg, const float* __restrict__ kb,
                                const float* __restrict__ vg, const float* __restrict__ vb,
                                float* __restrict__ scale, float* __restrict__ shift)
{
    const int c = threadIdx.x;
    if (c < CKV) {
        const float inv = 1.f / (float)(Bz * Nn);
        const float m = gsum[c] * inv;
        const float v = fmaf(-m, m, gsq[c] * inv);
        float ga, be;
        if (c < 12) { ga = kg[c]; be = kb[c]; }
        else        { ga = vg[c - 12]; be = vb[c - 12]; }
        const float sc = ga * rsqrtf(v + 1e-5f);
        scale[c] = sc;
        shift[c] = fmaf(-m, sc, be);
    }
}

// ---------------- Pass 3a: per-point transform -> record + (g,x0,y0,z0) histogram ----------------
__global__ __launch_bounds__(256) void points_kernel(
    const float* __restrict__ keys, const float* __restrict__ orig,
    const float* __restrict__ Rm, const float* __restrict__ tv,
    const float* __restrict__ scale, const float* __restrict__ shift,
    float4* __restrict__ rec, int* __restrict__ cnt)
{
    const int bid = blockIdx.x;
    const int g   = bid >> 6;
    const int b   = g >> 2;
    const int h   = g & 3;
    const int t   = threadIdx.x;
    const int n   = ((bid & 63) << 8) + t;

    __shared__ float sR[9], st3[3], ksc[3], ksh[3];
    if (t < 9)       sR[t] = Rm[h * 9 + t];
    else if (t < 12) st3[t - 9] = tv[h * 3 + (t - 9)];
    else if (t < 15) { ksc[t - 12] = scale[h * 3 + (t - 12)];
                       ksh[t - 12] = shift[h * 3 + (t - 12)]; }
    __syncthreads();

    const float k0 = fmaf(keys[(size_t)(g * 3 + 0) * Nn + n], ksc[0], ksh[0]);
    const float k1 = fmaf(keys[(size_t)(g * 3 + 1) * Nn + n], ksc[1], ksh[1]);
    const float k2 = fmaf(keys[(size_t)(g * 3 + 2) * Nn + n], ksc[2], ksh[2]);
    const float p0 = orig[(size_t)(b * 3 + 0) * Nn + n] + k0;
    const float p1 = orig[(size_t)(b * 3 + 1) * Nn + n] + k1;
    const float p2 = orig[(size_t)(b * 3 + 2) * Nn + n] + k2;

    int   idx[3];
    float loc[3];
    #pragma unroll
    for (int d = 0; d < 3; ++d) {
        const float tk = fmaf(sR[d*3+0], p0, fmaf(sR[d*3+1], p1, fmaf(sR[d*3+2], p2, st3[d])));
        const float la = tanhf(tk);
        const float po = (la + 1.f) * 15.5f;
        float fi = floorf(po);
        fi = fminf(fmaxf(fi, 0.f), 30.f);
        idx[d] = (int)fi;
        loc[d] = po - fi;
    }

    const unsigned meta = (unsigned)n | ((unsigned)idx[2] << 14) |
                          ((unsigned)idx[1] << 19) | ((unsigned)idx[0] << 24);
    float4 r;
    r.x = __uint_as_float(meta);
    r.y = loc[0]; r.z = loc[1]; r.w = loc[2];
    rec[(size_t)g * Nn + n] = r;
    const int key = ((g * NBX + idx[0]) * NBY + idx[1]) * NBZ + idx[2];
    atomicAdd(&cnt[key], 1);
}

// ---------------- Pass 3b: hierarchical exclusive scan over 953312 bins ----------------
__global__ __launch_bounds__(256) void scan1_kernel(const int* __restrict__ cnt,
                                                    int* __restrict__ bsum)
{
    __shared__ int s[256];
    const int t = threadIdx.x;
    const int i = blockIdx.x * 1024 + t * 4;
    int v = 0;
    #pragma unroll
    for (int j = 0; j < 4; ++j) { const int idx = i + j; if (idx < NB2) v += cnt[idx]; }
    s[t] = v;
    __syncthreads();
    for (int off = 128; off > 0; off >>= 1) {
        if (t < off) s[t] += s[t + off];
        __syncthreads();
    }
    if (t == 0) bsum[blockIdx.x] = s[0];
}

__global__ __launch_bounds__(1024) void scan2_kernel(const int* __restrict__ bsum,
                                                     int* __restrict__ bscan)
{
    __shared__ int s[1024];
    const int t = threadIdx.x;
    const int v = (t < NCH) ? bsum[t] : 0;
    s[t] = v;
    __syncthreads();
    for (int off = 1; off < 1024; off <<= 1) {
        const int x = (t >= off) ? s[t - off] : 0;
        __syncthreads();
        s[t] += x;
        __syncthreads();
    }
    if (t < NCH) bscan[t] = s[t] - v;   // exclusive
}

__global__ __launch_bounds__(256) void scan3_kernel(const int* __restrict__ cnt,
                                                    const int* __restrict__ bscan,
                                                    int* __restrict__ basep,
                                                    int* __restrict__ cursor)
{
    __shared__ int s[256];
    const int t = threadIdx.x;
    const int i = blockIdx.x * 1024 + t * 4;
    int c[4], l[4];
    int sum = 0;
    #pragma unroll
    for (int j = 0; j < 4; ++j) {
        const int idx = i + j;
        c[j] = (idx < NB2) ? cnt[idx] : 0;
        l[j] = sum; sum += c[j];
    }
    s[t] = sum;
    __syncthreads();
    for (int off = 1; off < 256; off <<= 1) {
        const int x = (t >= off) ? s[t - off] : 0;
        __syncthreads();
        s[t] += x;
        __syncthreads();
    }
    const int off0 = bscan[blockIdx.x] + s[t] - sum;
    #pragma unroll
    for (int j = 0; j < 4; ++j) {
        const int idx = i + j;
        if (idx < NB2) { basep[idx] = off0 + l[j]; cursor[idx] = off0 + l[j]; }
    }
}

// ---------------- Pass 3c: counting-sort records into (g,x0,y0,z0) bins ----------------
__global__ __launch_bounds__(256) void fill_kernel(
    const float4* __restrict__ rec, int* __restrict__ cursor,
    float4* __restrict__ binned)
{
    const int bid = blockIdx.x;
    const int g   = bid >> 6;
    const int t   = threadIdx.x;
    const int n   = ((bid & 63) << 8) + t;
    const float4 r = rec[(size_t)g * Nn + n];
    const unsigned meta = __float_as_uint(r.x);
    const int x0 = (meta >> 24) & 31;
    const int y0 = (meta >> 19) & 31;
    const int z0 = (meta >> 14) & 31;
    const int key = ((g * NBX + x0) * NBY + y0) * NBZ + z0;
    const int pos = atomicAdd(&cursor[key], 1);
    binned[pos] = r;
}

// ---------------- Pass 3d: gather via MFMA outer products — quarter-height blocks ----------------
// Grid: 4096 blocks = g | x<<5 | yq<<10; 512 threads = 8 waves; wave w owns row y = yq*8+w.
// Tile 8x32x32 = 32 KB -> up to 4 blocks/CU; small blocks equalize y-density imbalance.
#define MKAB(qe, ridx, ae, ve)                                               \
{                                                                            \
    const unsigned mq = __float_as_uint((qe).x);                             \
    const int z0 = (int)((mq >> 14) & 31u);                                  \
    const float wx  = dx ? (1.f - (qe).y) : (qe).y;                          \
    const float wy  = dy ? (1.f - (qe).z) : (qe).z;                          \
    const float wxy = ((ridx) < e) ? wx * wy : 0.f;                          \
    const float lz  = (qe).w;                                                \
    ae = (ln == z0) ? (1.f - lz) * wxy                                       \
                    : ((ln == z0 + 1) ? lz * wxy : 0.f);                     \
    ve = fmaf(vg[(((size_t)(mq & 16383u)) << 5) + ln], scf, shf);            \
}

__global__ __launch_bounds__(512) void gather_kernel(
    const float* __restrict__ vals, const float4* __restrict__ binned,
    const int* __restrict__ basep, const int* __restrict__ cnt,
    const float* __restrict__ scale, const float* __restrict__ shift,
    float* __restrict__ out)
{
    __shared__ float tile[8192];
    __shared__ float sscale[32], sshift[32];

    const int bid = blockIdx.x;
    const int g   = bid & 31;
    const int x   = (bid >> 5) & 31;
    const int yq  = bid >> 10;        // 0..3
    const int h   = g & 3;
    const int t   = threadIdx.x;

    if (t < 32) { sscale[t] = scale[12 + h * 32 + t]; sshift[t] = shift[12 + h * 32 + t]; }
    __syncthreads();

    const int ln = t & 31;            // A row (z) / B col (f)
    const int hi = (t >> 5) & 1;      // k-octet select
    const int w  = t >> 6;            // wave id 0..7
    const int y  = (yq << 3) + w;     // owned output row
    const float scf = sscale[ln], shf = sshift[ln];
    const float* vg = vals + ((size_t)g << 19);   // g * Nn * Ff

    f32x16 acc;
    #pragma unroll
    for (int j = 0; j < 16; ++j) acc[j] = 0.f;

    #pragma unroll
    for (int dy = 0; dy < 2; ++dy) {
        const int y0 = y - 1 + dy;                // dy=0: wy=q.z ; dy=1: wy=1-q.z
        if ((unsigned)y0 > 30u) continue;
        #pragma unroll
        for (int dx = 0; dx < 2; ++dx) {
            const int x0 = x - 1 + dx;
            if ((unsigned)x0 > 30u) continue;
            const int kb = ((g * NBX + x0) * NBY + y0) * NBZ;
            int r       = basep[kb];
            const int e = basep[kb + 30] + cnt[kb + 30];

            for (; r < e; r += 16) {
                const int base = r + (hi << 3);
                const int eM1  = e - 1;
                const int r0 = min(base,     eM1);
                const int r1 = min(base + 1, eM1);
                const int r2 = min(base + 2, eM1);
                const int r3 = min(base + 3, eM1);
                const int r4 = min(base + 4, eM1);
                const int r5 = min(base + 5, eM1);
                const int r6 = min(base + 6, eM1);
                const int r7 = min(base + 7, eM1);
                const float4 q0 = binned[r0];
                const float4 q1 = binned[r1];
                const float4 q2 = binned[r2];
                const float4 q3 = binned[r3];
                const float4 q4 = binned[r4];
                const float4 q5 = binned[r5];
                const float4 q6 = binned[r6];
                const float4 q7 = binned[r7];
                float a0, a1, a2, a3, a4, a5, a6, a7;
                float v0, v1, v2, v3, v4, v5, v6, v7;
                MKAB(q0, base,     a0, v0);
                MKAB(q1, base + 1, a1, v1);
                MKAB(q2, base + 2, a2, v2);
                MKAB(q3, base + 3, a3, v3);
                MKAB(q4, base + 4, a4, v4);
                MKAB(q5, base + 5, a5, v5);
                MKAB(q6, base + 6, a6, v6);
                MKAB(q7, base + 7, a7, v7);
                union { bf16x8 v; unsigned u[4]; } af, bf;
                af.u[0] = cvt2(a0, a1); af.u[1] = cvt2(a2, a3);
                af.u[2] = cvt2(a4, a5); af.u[3] = cvt2(a6, a7);
                bf.u[0] = cvt2(v0, v1); bf.u[1] = cvt2(v2, v3);
                bf.u[2] = cvt2(v4, v5); bf.u[3] = cvt2(v6, v7);
                acc = __builtin_amdgcn_mfma_f32_32x32x16_bf16(af.v, bf.v, acc, 0, 0, 0);
            }
        }
    }

    // write acc -> wave tile: C[row=z][col=f], stored swizzled [z][f^z]
    float* const tg = &tile[w << 10];
    #pragma unroll
    for (int reg = 0; reg < 16; ++reg) {
        const int zr = (reg & 3) + ((reg >> 2) << 3) + (hi << 2);
        tg[(zr << 5) + ((ln ^ zr) & 31)] = acc[reg];
    }
    __syncthreads();

    // write out[(g*32+fp)*G3 + x*1024 + (yq*8+row)*32 + z]
    float* og = out + ((size_t)g << 20) + (x << 10) + (yq << 8);
    #pragma unroll
    for (int i = 0; i < 16; ++i) {
        const int lin = t + (i << 9);      // 0..8191
        const int fp  = lin >> 8;          // 0..31
        const int s   = lin & 255;         // row*32 + z
        const int z   = s & 31;
        og[((size_t)fp << 15) + s] = tile[((s >> 5) << 10) + (z << 5) + ((fp ^ z) & 31)];
    }
}

// ---------------- Fallback: direct-layout global-atomic scatter ----------------
__global__ __launch_bounds__(256) void scatter_kernel(
    const float* __restrict__ vals, const float* __restrict__ keys,
    const float* __restrict__ orig, const float* __restrict__ Rm,
    const float* __restrict__ tv, const float* __restrict__ scale,
    const float* __restrict__ shift, float* __restrict__ out)
{
    const int bid   = blockIdx.x;
    const int g     = bid >> 5;
    const int chunk = bid & 31;
    const int b     = g >> 2;
    const int h     = g & 3;

    __shared__ float sc[32], sh[32], sR[9], st3[3], ksc[3], ksh[3];
    const int t = threadIdx.x;
    if (t < 32)      { sc[t] = scale[12 + h * 32 + t]; sh[t] = shift[12 + h * 32 + t]; }
    else if (t < 41) { sR[t - 32]  = Rm[h * 9 + (t - 32)]; }
    else if (t < 44) { st3[t - 41] = tv[h * 3 + (t - 41)]; }
    else if (t < 47) { ksc[t - 44] = scale[h * 3 + (t - 44)];
                       ksh[t - 44] = shift[h * 3 + (t - 44)]; }
    __syncthreads();

    float* const og = out + ((size_t)g << 20);

    #pragma unroll
    for (int pp = 0; pp < 2; ++pp) {
        const int n = (chunk << 9) + (pp << 8) + t;

        const float k0 = fmaf(keys[(size_t)(g * 3 + 0) * Nn + n], ksc[0], ksh[0]);
        const float k1 = fmaf(keys[(size_t)(g * 3 + 1) * Nn + n], ksc[1], ksh[1]);
        const float k2 = fmaf(keys[(size_t)(g * 3 + 2) * Nn + n], ksc[2], ksh[2]);
        const float p0 = orig[(size_t)(b * 3 + 0) * Nn + n] + k0;
        const float p1 = orig[(size_t)(b * 3 + 1) * Nn + n] + k1;
        const float p2 = orig[(size_t)(b * 3 + 2) * Nn + n] + k2;

        int   idx[3];
        float loc[3];
        #pragma unroll
        for (int d = 0; d < 3; ++d) {
            const float tk = fmaf(sR[d*3+0], p0, fmaf(sR[d*3+1], p1, fmaf(sR[d*3+2], p2, st3[d])));
            const float la = tanhf(tk);
            const float po = (la + 1.f) * 15.5f;
            float fi = floorf(po);
            fi = fminf(fmaxf(fi, 0.f), 30.f);
            idx[d] = (int)fi;
            loc[d] = po - fi;
        }
        const int cell = (idx[0] * Gg + idx[1]) * Gg + idx[2];

        float v[32];
        const float4* vp = reinterpret_cast<const float4*>(vals + ((size_t)g * Nn + n) * Ff);
        #pragma unroll
        for (int q = 0; q < 8; ++q) {
            const float4 xq = vp[q];
            v[4*q+0] = fmaf(xq.x, sc[4*q+0], sh[4*q+0]);
            v[4*q+1] = fmaf(xq.y, sc[4*q+1], sh[4*q+1]);
            v[4*q+2] = fmaf(xq.z, sc[4*q+2], sh[4*q+2]);
            v[4*q+3] = fmaf(xq.w, sc[4*q+3], sh[4*q+3]);
        }

        const float wx1 = loc[0], wx0 = 1.f - loc[0];
        const float wy1 = loc[1], wy0 = 1.f - loc[1];
        const float wz1 = loc[2], wz0 = 1.f - loc[2];
        const float cw[8] = { wx0*wy0*wz0, wx0*wy0*wz1, wx0*wy1*wz0, wx0*wy1*wz1,
                              wx1*wy0*wz0, wx1*wy0*wz1, wx1*wy1*wz0, wx1*wy1*wz1 };
        const int  co[8] = { 0, 1, 32, 33, 1024, 1025, 1056, 1057 };

        #pragma unroll
        for (int ff = 0; ff < 32; ++ff) {
            float* const pf = og + (size_t)ff * G3v + cell;
            const float vf = v[ff];
            #pragma unroll
            for (int c8 = 0; c8 < 8; ++c8) {
                atomicAdd(pf + co[c8], cw[c8] * vf);
            }
        }
    }
}

extern "C" void kernel_launch(void* const* d_in, const int* in_sizes, int n_in,
                              void* d_out, int out_size, void* d_ws, size_t ws_size,
                              hipStream_t stream)
{
    const float* X    = (const float*)d_in[0];
    const float* orig = (const float*)d_in[1];
    const float* W    = (const float*)d_in[2];
    const float* kg   = (const float*)d_in[3];
    const float* kb   = (const float*)d_in[4];
    const float* vg   = (const float*)d_in[5];
    const float* vb   = (const float*)d_in[6];
    const float* Rm   = (const float*)d_in[7];
    const float* tv   = (const float*)d_in[8];
    float* out = (float*)d_out;
    float* ws  = (float*)d_ws;

    // float-offset workspace layout
    float* vals  = ws;                          // 16,777,216
    float* keys  = ws + 16777216;               //  1,572,864
    float* gsum  = ws + 18350080;               // 140
    float* gsq   = gsum + 140;
    float* scale = gsum + 280;
    float* shift = scale + 140;
    int*   cnt    = (int*)(ws + 18350848);      // 953,312
    int*   basep  = (int*)(ws + 19304160);      // 953,312
    int*   cursor = (int*)(ws + 20257472);      // 953,312
    int*   bsum   = (int*)(ws + 21210784);      // 1,024
    int*   bscan  = (int*)(ws + 21211808);      // 1,024
    float4* rec    = (float4*)(ws + 21212832);  // 524,288 float4
    float4* binned = (float4*)(ws + 23309984);  // 524,288 float4
    unsigned short* Wbf = (unsigned short*)(ws + 25407136); // 40,960 bf16
    const size_t need_bytes = (size_t)25427616 * sizeof(float);   // ~101.7 MiB

    hipMemsetAsync(gsum, 0, 280 * sizeof(float), stream);

    prep_w_kernel<<<160, 256, 0, stream>>>(W, Wbf);
    gemm_stats_kernel<<<1024, 256, 0, stream>>>(X, Wbf, vals, keys);
    stats_keys_kernel<<<32, 256, 0, stream>>>(keys, gsum, gsq);
    stats_vals_kernel<<<1024, 256, 0, stream>>>(vals, gsum, gsq);
    finalize_kernel<<<1, 256, 0, stream>>>(gsum, gsq, kg, kb, vg, vb, scale, shift);

    if (ws_size >= need_bytes) {
        hipMemsetAsync(cnt, 0, (size_t)NB2 * sizeof(int), stream);
        points_kernel<<<2048, 256, 0, stream>>>(keys, orig, Rm, tv, scale, shift, rec, cnt);
        scan1_kernel<<<NCH, 256, 0, stream>>>(cnt, bsum);
        scan2_kernel<<<1, 1024, 0, stream>>>(bsum, bscan);
        scan3_kernel<<<NCH, 256, 0, stream>>>(cnt, bscan, basep, cursor);
        fill_kernel<<<2048, 256, 0, stream>>>(rec, cursor, binned);
        gather_kernel<<<4096, 512, 0, stream>>>(vals, binned, basep, cnt, scale, shift, out);
    } else {
        hipMemsetAsync(out, 0, (size_t)out_size * sizeof(float), stream);
        scatter_kernel<<<1024, 256, 0, stream>>>(vals, keys, orig, Rm, tv, scale, shift, out);
    }
}